// Round 1
// baseline (883.171 us; speedup 1.0000x reference)
//
#include <hip/hip_runtime.h>
#include <hip/hip_bf16.h>

#define BN_EPS 1e-5f

// ---------------- edge dtype detection ----------------
// If edge_index is int64 (little-endian, values < 2^31), every odd 32-bit
// word is zero. With int32 random indices in [0,1e5), 64 consecutive odd
// words being all zero is impossible in practice.
__global__ void detect_kernel(const int* __restrict__ e32, int* __restrict__ flag) {
    if (threadIdx.x == 0 && blockIdx.x == 0) {
        int nz = 0;
        for (int i = 0; i < 64; ++i) nz += (e32[2*i + 1] != 0);
        *flag = (nz == 0) ? 1 : 0;
    }
}

__device__ __forceinline__ int edge_at(const void* p, long long i, int is64) {
    return is64 ? (int)((const long long*)p)[i] : ((const int*)p)[i];
}

// ---------------- degree count ----------------
__global__ void count_deg_kernel(const void* __restrict__ eidx, const int* __restrict__ flag,
                                 int* __restrict__ cnt, int E) {
    int e = blockIdx.x * blockDim.x + threadIdx.x;
    if (e >= E) return;
    int is64 = *flag;
    int d = edge_at(eidx, (long long)E + e, is64);
    atomicAdd(&cnt[d], 1);
}

__global__ void dis_kernel(const int* __restrict__ cnt, float* __restrict__ dis, int N) {
    int n = blockIdx.x * blockDim.x + threadIdx.x;
    if (n < N) dis[n] = rsqrtf((float)cnt[n] + 1.0f);
}

// ---------------- prefix scan (3-phase) ----------------
__global__ void scan_partial_kernel(const int* __restrict__ cnt, int* __restrict__ rp,
                                    int* __restrict__ bsum, int n) {
    __shared__ int s[256];
    const int t = threadIdx.x;
    const int i = blockIdx.x * 256 + t;
    int v = (i < n) ? cnt[i] : 0;
    s[t] = v;
    __syncthreads();
    for (int off = 1; off < 256; off <<= 1) {
        int x = (t >= off) ? s[t - off] : 0;
        __syncthreads();
        s[t] += x;
        __syncthreads();
    }
    if (i < n) rp[i + 1] = s[t];           // inclusive within block
    if (t == 255) bsum[blockIdx.x] = s[255];
}

__global__ void scan_blocks_kernel(int* __restrict__ bs, int nb) {
    __shared__ int s[512];
    __shared__ int carry_s;
    const int t = threadIdx.x;
    if (t == 0) carry_s = 0;
    __syncthreads();
    for (int base = 0; base < nb; base += 512) {
        int v = (base + t < nb) ? bs[base + t] : 0;
        s[t] = v;
        __syncthreads();
        for (int off = 1; off < 512; off <<= 1) {
            int x = (t >= off) ? s[t - off] : 0;
            __syncthreads();
            s[t] += x;
            __syncthreads();
        }
        int inc = s[t];
        int total = s[511];
        int carry = carry_s;
        __syncthreads();
        if (base + t < nb) bs[base + t] = inc - v + carry;  // exclusive
        if (t == 0) carry_s = carry + total;
        __syncthreads();
    }
}

__global__ void scan_add_kernel(int* __restrict__ rp, int* __restrict__ cursor,
                                const int* __restrict__ cnt, const int* __restrict__ bsum, int n) {
    int i = blockIdx.x * 256 + threadIdx.x;
    if (i < n) {
        int off = bsum[blockIdx.x];
        int incl = rp[i + 1] + off;
        rp[i + 1] = incl;
        cursor[i] = incl - cnt[i];   // exclusive prefix = bucket start
    }
    if (i == 0) rp[0] = 0;
}

// ---------------- bucket fill (sort edges by dst) ----------------
__global__ void fill_kernel(const void* __restrict__ eidx, const int* __restrict__ flag,
                            const float* __restrict__ dis, int* __restrict__ cursor,
                            int* __restrict__ e_src, float* __restrict__ e_w, int E) {
    int e = blockIdx.x * blockDim.x + threadIdx.x;
    if (e >= E) return;
    int is64 = *flag;
    int s = edge_at(eidx, e, is64);
    int d = edge_at(eidx, (long long)E + e, is64);
    int pos = atomicAdd(&cursor[d], 1);
    e_src[pos] = s;
    e_w[pos]  = dis[s] * dis[d];
}

// ---------------- GEMM: out[N][DOUT] = H[N][128] @ W[128][DOUT], bf16 out ----------------
template <int DOUT>
__global__ __launch_bounds__(256) void gemm_kernel(const float* __restrict__ H,
                                                   const float* __restrict__ W,
                                                   __hip_bfloat16* __restrict__ out, int N) {
    constexpr int ROWS = 4096 / DOUT;   // 32 (D=128) or 64 (D=64)
    constexpr int CG   = DOUT / 4;      // col groups of 4
    __shared__ float sW[64 * DOUT];
    __shared__ float sH[ROWS * 64];
    const int t   = threadIdx.x;
    const int cg  = t % CG;
    const int rg  = t / CG;
    const int row0 = blockIdx.x * ROWS;
    float acc[4][4] = {{0.f}};
    for (int kb = 0; kb < 128; kb += 64) {
        // stage W tile (rows kb..kb+63, contiguous)
        for (int i = t; i < 64 * DOUT / 4; i += 256)
            ((float4*)sW)[i] = ((const float4*)(W + (size_t)kb * DOUT))[i];
        // stage H tile: one wave loads one row (64 k-values) per iteration
        {
            const int r = t >> 6, l = t & 63;
            for (int rr = r; rr < ROWS; rr += 4) {
                int grow = row0 + rr;
                sH[rr * 64 + l] = (grow < N) ? H[(size_t)grow * 128 + kb + l] : 0.f;
            }
        }
        __syncthreads();
#pragma unroll 8
        for (int k = 0; k < 64; ++k) {
            const float4 wv = *(const float4*)(&sW[k * DOUT + cg * 4]);
            float hv[4];
#pragma unroll
            for (int i = 0; i < 4; ++i) hv[i] = sH[(rg * 4 + i) * 64 + k];
#pragma unroll
            for (int i = 0; i < 4; ++i) {
                acc[i][0] += hv[i] * wv.x;
                acc[i][1] += hv[i] * wv.y;
                acc[i][2] += hv[i] * wv.z;
                acc[i][3] += hv[i] * wv.w;
            }
        }
        __syncthreads();
    }
#pragma unroll
    for (int i = 0; i < 4; ++i) {
        int grow = row0 + rg * 4 + i;
        if (grow < N) {
            __hip_bfloat16* op = out + (size_t)grow * DOUT + cg * 4;
            __hip_bfloat162 p0, p1;
            p0.x = __float2bfloat16(acc[i][0]);
            p0.y = __float2bfloat16(acc[i][1]);
            p1.x = __float2bfloat16(acc[i][2]);
            p1.y = __float2bfloat16(acc[i][3]);
            ((__hip_bfloat162*)op)[0] = p0;
            ((__hip_bfloat162*)op)[1] = p1;
        }
    }
}

// ---------------- aggregation: out[n] = sum_{e in CSR[n]} hw[src_e]*w_e + hw[n]*dis[n]^2 + b ----------------
template <int D>
__global__ void agg_kernel(const __hip_bfloat16* __restrict__ hw, const int* __restrict__ rp,
                           const int* __restrict__ e_src, const float* __restrict__ e_w,
                           const float* __restrict__ dis, const float* __restrict__ bias,
                           float* __restrict__ out, int N) {
    constexpr int LPR = D / 2;                       // lanes per row (2 floats each)
    int gtid = blockIdx.x * blockDim.x + threadIdx.x;
    int n    = gtid / LPR;
    int lane = gtid % LPR;
    if (n >= N) return;
    float sn = dis[n] * dis[n];
    __hip_bfloat162 hv = ((const __hip_bfloat162*)hw)[(size_t)n * LPR + lane];
    float ax = __bfloat162float(hv.x) * sn;
    float ay = __bfloat162float(hv.y) * sn;
    int e0 = rp[n], e1 = rp[n + 1];
    for (int e = e0; e < e1; ++e) {
        int s   = e_src[e];
        float w = e_w[e];
        __hip_bfloat162 v = ((const __hip_bfloat162*)hw)[(size_t)s * LPR + lane];
        ax += __bfloat162float(v.x) * w;
        ay += __bfloat162float(v.y) * w;
    }
    float2 bv = ((const float2*)bias)[lane];
    ((float2*)out)[(size_t)n * LPR + lane] = make_float2(ax + bv.x, ay + bv.y);
}

// ---------------- batchnorm ----------------
__global__ void bn_stats_kernel(const float* __restrict__ X, float* __restrict__ stats, int N) {
    const int t = threadIdx.x;
    const int col = t & 127;
    const int half = t >> 7;
    float s = 0.f, s2 = 0.f;
    for (int r = blockIdx.x * 2 + half; r < N; r += gridDim.x * 2) {
        float v = X[(size_t)r * 128 + col];
        s += v;
        s2 += v * v;
    }
    __shared__ float ls[256], ls2[256];
    ls[t] = s; ls2[t] = s2;
    __syncthreads();
    if (t < 128) {
        s  = ls[t] + ls[t + 128];
        s2 = ls2[t] + ls2[t + 128];
        atomicAdd(&stats[col], s);
        atomicAdd(&stats[col + 128], s2);
    }
}

__global__ void bn_finalize_kernel(float* __restrict__ stats, const float* __restrict__ g,
                                   const float* __restrict__ be, float invN) {
    int c = threadIdx.x;
    if (c < 128) {
        float mu  = stats[c] * invN;
        float var = stats[c + 128] * invN - mu * mu;
        float sc  = g[c] * rsqrtf(var + BN_EPS);
        stats[c]       = sc;
        stats[c + 128] = be[c] - mu * sc;
    }
}

__global__ void bn_apply_kernel(float* __restrict__ X, const float* __restrict__ stats, long long n4) {
    long long i0 = (long long)blockIdx.x * blockDim.x + threadIdx.x;
    long long stride = (long long)gridDim.x * blockDim.x;
    for (long long p = i0; p < n4; p += stride) {
        int c4 = ((int)(p & 31)) * 4;
        float4 v = ((float4*)X)[p];
        v.x = fmaxf(v.x * stats[c4 + 0] + stats[128 + c4 + 0], 0.f);
        v.y = fmaxf(v.y * stats[c4 + 1] + stats[128 + c4 + 1], 0.f);
        v.z = fmaxf(v.z * stats[c4 + 2] + stats[128 + c4 + 2], 0.f);
        v.w = fmaxf(v.w * stats[c4 + 3] + stats[128 + c4 + 3], 0.f);
        ((float4*)X)[p] = v;
    }
}

// ---------------- host launch ----------------
extern "C" void kernel_launch(void* const* d_in, const int* in_sizes, int n_in,
                              void* d_out, int out_size, void* d_ws, size_t ws_size,
                              hipStream_t stream) {
    const float* x   = (const float*)d_in[0];
    const void*  eix = d_in[1];
    const float* W1  = (const float*)d_in[2];
    const float* b1  = (const float*)d_in[3];
    const float* g1  = (const float*)d_in[4];
    const float* be1 = (const float*)d_in[5];
    const float* W2  = (const float*)d_in[6];
    const float* b2  = (const float*)d_in[7];
    const float* g2  = (const float*)d_in[8];
    const float* be2 = (const float*)d_in[9];
    const float* W3  = (const float*)d_in[10];
    const float* b3  = (const float*)d_in[11];
    float* outp = (float*)d_out;

    const int N = in_sizes[0] / 128;
    const int E = in_sizes[1] / 2;

    // workspace layout
    char* base = (char*)d_ws;
    size_t off = 0;
    auto alloc = [&](size_t bytes) -> char* {
        char* p = base + off;
        off = (off + bytes + 255) & ~(size_t)255;
        return p;
    };
    __hip_bfloat16* A = (__hip_bfloat16*)alloc((size_t)N * 128 * 2); // hw (bf16)
    float* B          = (float*)alloc((size_t)N * 128 * 4);          // pre/post-BN h (f32)
    int*   cnt        = (int*)alloc((size_t)N * 4);
    int*   rp         = (int*)alloc((size_t)(N + 1) * 4);
    int*   cursor     = (int*)alloc((size_t)N * 4);
    float* dis        = (float*)alloc((size_t)N * 4);
    int*   e_src      = (int*)alloc((size_t)E * 4);
    float* e_w        = (float*)alloc((size_t)E * 4);
    int*   bsum       = (int*)alloc(4096);
    float* stats      = (float*)alloc(256 * 4);
    int*   flag       = (int*)alloc(64);
    (void)ws_size; (void)n_in; (void)out_size;

    const int SB = (N + 255) / 256;

    // ---- graph preprocessing ----
    hipMemsetAsync(cnt, 0, (size_t)N * 4, stream);
    detect_kernel<<<1, 64, 0, stream>>>((const int*)eix, flag);
    count_deg_kernel<<<(E + 255) / 256, 256, 0, stream>>>(eix, flag, cnt, E);
    dis_kernel<<<(N + 255) / 256, 256, 0, stream>>>(cnt, dis, N);
    scan_partial_kernel<<<SB, 256, 0, stream>>>(cnt, rp, bsum, N);
    scan_blocks_kernel<<<1, 512, 0, stream>>>(bsum, SB);
    scan_add_kernel<<<SB, 256, 0, stream>>>(rp, cursor, cnt, bsum, N);
    fill_kernel<<<(E + 255) / 256, 256, 0, stream>>>(eix, flag, dis, cursor, e_src, e_w, E);

    const float invN = 1.0f / (float)N;
    const int gemm128_grid = (N + 31) / 32;
    const int gemm64_grid  = (N + 63) / 64;
    const int agg128_grid  = (int)(((long long)N * 64 + 255) / 256);
    const int agg64_grid   = (int)(((long long)N * 32 + 255) / 256);

    // ---- layer 1 ----
    gemm_kernel<128><<<gemm128_grid, 256, 0, stream>>>(x, W1, A, N);
    agg_kernel<128><<<agg128_grid, 256, 0, stream>>>(A, rp, e_src, e_w, dis, b1, B, N);
    hipMemsetAsync(stats, 0, 256 * 4, stream);
    bn_stats_kernel<<<256, 256, 0, stream>>>(B, stats, N);
    bn_finalize_kernel<<<1, 128, 0, stream>>>(stats, g1, be1, invN);
    bn_apply_kernel<<<2048, 256, 0, stream>>>(B, stats, (long long)N * 32);

    // ---- layer 2 ----
    gemm_kernel<128><<<gemm128_grid, 256, 0, stream>>>(B, W2, A, N);
    agg_kernel<128><<<agg128_grid, 256, 0, stream>>>(A, rp, e_src, e_w, dis, b2, B, N);
    hipMemsetAsync(stats, 0, 256 * 4, stream);
    bn_stats_kernel<<<256, 256, 0, stream>>>(B, stats, N);
    bn_finalize_kernel<<<1, 128, 0, stream>>>(stats, g2, be2, invN);
    bn_apply_kernel<<<2048, 256, 0, stream>>>(B, stats, (long long)N * 32);

    // ---- layer 3 (no BN/relu) ----
    gemm_kernel<64><<<gemm64_grid, 256, 0, stream>>>(B, W3, A, N);
    agg_kernel<64><<<agg64_grid, 256, 0, stream>>>(A, rp, e_src, e_w, dis, b3, outp, N);
}

// Round 2
// 628.404 us; speedup vs baseline: 1.4054x; 1.4054x over previous
//
#include <hip/hip_runtime.h>
#include <hip/hip_bf16.h>

#define BN_EPS 1e-5f

// ---------------- edge dtype detection ----------------
__global__ void detect_kernel(const int* __restrict__ e32, int* __restrict__ flag) {
    if (threadIdx.x == 0 && blockIdx.x == 0) {
        int nz = 0;
        for (int i = 0; i < 64; ++i) nz += (e32[2*i + 1] != 0);
        *flag = (nz == 0) ? 1 : 0;
    }
}

__device__ __forceinline__ int edge_at(const void* p, long long i, int is64) {
    return is64 ? (int)((const long long*)p)[i] : ((const int*)p)[i];
}

// ---------------- degree count ----------------
__global__ void count_deg_kernel(const void* __restrict__ eidx, const int* __restrict__ flag,
                                 int* __restrict__ cnt, int E) {
    int e = blockIdx.x * blockDim.x + threadIdx.x;
    if (e >= E) return;
    int is64 = *flag;
    int d = edge_at(eidx, (long long)E + e, is64);
    atomicAdd(&cnt[d], 1);
}

__global__ void dis_kernel(const int* __restrict__ cnt, float* __restrict__ dis, int N) {
    int n = blockIdx.x * blockDim.x + threadIdx.x;
    if (n < N) dis[n] = rsqrtf((float)cnt[n] + 1.0f);
}

// ---------------- prefix scan (3-phase) ----------------
__global__ void scan_partial_kernel(const int* __restrict__ cnt, int* __restrict__ rp,
                                    int* __restrict__ bsum, int n) {
    __shared__ int s[256];
    const int t = threadIdx.x;
    const int i = blockIdx.x * 256 + t;
    int v = (i < n) ? cnt[i] : 0;
    s[t] = v;
    __syncthreads();
    for (int off = 1; off < 256; off <<= 1) {
        int x = (t >= off) ? s[t - off] : 0;
        __syncthreads();
        s[t] += x;
        __syncthreads();
    }
    if (i < n) rp[i + 1] = s[t];
    if (t == 255) bsum[blockIdx.x] = s[255];
}

__global__ void scan_blocks_kernel(int* __restrict__ bs, int nb) {
    __shared__ int s[512];
    __shared__ int carry_s;
    const int t = threadIdx.x;
    if (t == 0) carry_s = 0;
    __syncthreads();
    for (int base = 0; base < nb; base += 512) {
        int v = (base + t < nb) ? bs[base + t] : 0;
        s[t] = v;
        __syncthreads();
        for (int off = 1; off < 512; off <<= 1) {
            int x = (t >= off) ? s[t - off] : 0;
            __syncthreads();
            s[t] += x;
            __syncthreads();
        }
        int inc = s[t];
        int total = s[511];
        int carry = carry_s;
        __syncthreads();
        if (base + t < nb) bs[base + t] = inc - v + carry;
        if (t == 0) carry_s = carry + total;
        __syncthreads();
    }
}

__global__ void scan_add_kernel(int* __restrict__ rp, int* __restrict__ cursor,
                                const int* __restrict__ cnt, const int* __restrict__ bsum, int n) {
    int i = blockIdx.x * 256 + threadIdx.x;
    if (i < n) {
        int off = bsum[blockIdx.x];
        int incl = rp[i + 1] + off;
        rp[i + 1] = incl;
        cursor[i] = incl - cnt[i];
    }
    if (i == 0) rp[0] = 0;
}

// ---------------- bucket fill: edges sorted by dst, packed (src, w) ----------------
__global__ void fill_kernel(const void* __restrict__ eidx, const int* __restrict__ flag,
                            const float* __restrict__ dis, int* __restrict__ cursor,
                            int2* __restrict__ ep, int E) {
    int e = blockIdx.x * blockDim.x + threadIdx.x;
    if (e >= E) return;
    int is64 = *flag;
    int s = edge_at(eidx, e, is64);
    int d = edge_at(eidx, (long long)E + e, is64);
    int pos = atomicAdd(&cursor[d], 1);
    float w = dis[s] * dis[d];
    ep[pos] = make_int2(s, __float_as_int(w));
}

// ---------------- GEMM: out[N][DOUT] = bnrelu(H)[N][128] @ W[128][DOUT], bf16 out ----------------
// BN=true: H is pre-BN; apply y = relu(H*scale[c]+shift[c]) while staging.
template <int DOUT, bool BN>
__global__ __launch_bounds__(256) void gemm_kernel(const float* __restrict__ H,
                                                   const float* __restrict__ W,
                                                   const float* __restrict__ bnst,
                                                   __hip_bfloat16* __restrict__ out, int N) {
    constexpr int ROWS = 4096 / DOUT;   // 32 (D=128) or 64 (D=64)
    constexpr int CG   = DOUT / 4;
    __shared__ float sW[64 * DOUT];
    __shared__ float sH[ROWS * 64];
    const int t   = threadIdx.x;
    const int cg  = t % CG;
    const int rg  = t / CG;
    const int row0 = blockIdx.x * ROWS;
    float acc[4][4] = {{0.f}};
    for (int kb = 0; kb < 128; kb += 64) {
        for (int i = t; i < 64 * DOUT / 4; i += 256)
            ((float4*)sW)[i] = ((const float4*)(W + (size_t)kb * DOUT))[i];
        {
            const int r = t >> 6, l = t & 63;
            float sc = 1.f, sh = 0.f;
            if (BN) { sc = bnst[kb + l]; sh = bnst[128 + kb + l]; }
            for (int rr = r; rr < ROWS; rr += 4) {
                int grow = row0 + rr;
                float v = (grow < N) ? H[(size_t)grow * 128 + kb + l] : 0.f;
                if (BN) v = fmaxf(v * sc + sh, 0.f);
                sH[rr * 64 + l] = v;
            }
        }
        __syncthreads();
#pragma unroll 8
        for (int k = 0; k < 64; ++k) {
            const float4 wv = *(const float4*)(&sW[k * DOUT + cg * 4]);
            float hv[4];
#pragma unroll
            for (int i = 0; i < 4; ++i) hv[i] = sH[(rg * 4 + i) * 64 + k];
#pragma unroll
            for (int i = 0; i < 4; ++i) {
                acc[i][0] += hv[i] * wv.x;
                acc[i][1] += hv[i] * wv.y;
                acc[i][2] += hv[i] * wv.z;
                acc[i][3] += hv[i] * wv.w;
            }
        }
        __syncthreads();
    }
#pragma unroll
    for (int i = 0; i < 4; ++i) {
        int grow = row0 + rg * 4 + i;
        if (grow < N) {
            __hip_bfloat16* op = out + (size_t)grow * DOUT + cg * 4;
            __hip_bfloat162 p0, p1;
            p0.x = __float2bfloat16(acc[i][0]);
            p0.y = __float2bfloat16(acc[i][1]);
            p1.x = __float2bfloat16(acc[i][2]);
            p1.y = __float2bfloat16(acc[i][3]);
            ((__hip_bfloat162*)op)[0] = p0;
            ((__hip_bfloat162*)op)[1] = p1;
        }
    }
}

// ---------------- aggregation with 4x unrolled edge loop ----------------
template <int D>
__global__ void agg_kernel(const __hip_bfloat16* __restrict__ hw, const int* __restrict__ rp,
                           const int2* __restrict__ ep, const float* __restrict__ dis,
                           const float* __restrict__ bias, float* __restrict__ out, int N) {
    constexpr int LPR = D / 2;
    int gtid = blockIdx.x * blockDim.x + threadIdx.x;
    int n    = gtid / LPR;
    int lane = gtid % LPR;
    if (n >= N) return;
    const __hip_bfloat162* hw2 = (const __hip_bfloat162*)hw;
    float sn = dis[n];
    sn *= sn;
    __hip_bfloat162 hv = hw2[(size_t)n * LPR + lane];
    float ax = __bfloat162float(hv.x) * sn;
    float ay = __bfloat162float(hv.y) * sn;
    int e0 = rp[n], e1 = rp[n + 1];
    int e = e0;
    for (; e + 4 <= e1; e += 4) {
        int2 p0 = ep[e + 0];
        int2 p1 = ep[e + 1];
        int2 p2 = ep[e + 2];
        int2 p3 = ep[e + 3];
        __hip_bfloat162 v0 = hw2[(size_t)p0.x * LPR + lane];
        __hip_bfloat162 v1 = hw2[(size_t)p1.x * LPR + lane];
        __hip_bfloat162 v2 = hw2[(size_t)p2.x * LPR + lane];
        __hip_bfloat162 v3 = hw2[(size_t)p3.x * LPR + lane];
        float w0 = __int_as_float(p0.y), w1 = __int_as_float(p1.y);
        float w2 = __int_as_float(p2.y), w3 = __int_as_float(p3.y);
        ax += __bfloat162float(v0.x) * w0; ay += __bfloat162float(v0.y) * w0;
        ax += __bfloat162float(v1.x) * w1; ay += __bfloat162float(v1.y) * w1;
        ax += __bfloat162float(v2.x) * w2; ay += __bfloat162float(v2.y) * w2;
        ax += __bfloat162float(v3.x) * w3; ay += __bfloat162float(v3.y) * w3;
    }
    for (; e < e1; ++e) {
        int2 p = ep[e];
        __hip_bfloat162 v = hw2[(size_t)p.x * LPR + lane];
        float w = __int_as_float(p.y);
        ax += __bfloat162float(v.x) * w;
        ay += __bfloat162float(v.y) * w;
    }
    float2 bv = ((const float2*)bias)[lane];
    ((float2*)out)[(size_t)n * LPR + lane] = make_float2(ax + bv.x, ay + bv.y);
}

// ---------------- batchnorm stats ----------------
__global__ void bn_stats_kernel(const float* __restrict__ X, float* __restrict__ stats, int N) {
    const int t = threadIdx.x;
    const int col = t & 127;
    const int half = t >> 7;
    float s = 0.f, s2 = 0.f;
    for (int r = blockIdx.x * 2 + half; r < N; r += gridDim.x * 2) {
        float v = X[(size_t)r * 128 + col];
        s += v;
        s2 += v * v;
    }
    __shared__ float ls[256], ls2[256];
    ls[t] = s; ls2[t] = s2;
    __syncthreads();
    if (t < 128) {
        s  = ls[t] + ls[t + 128];
        s2 = ls2[t] + ls2[t + 128];
        atomicAdd(&stats[col], s);
        atomicAdd(&stats[col + 128], s2);
    }
}

__global__ void bn_finalize_kernel(float* __restrict__ stats, const float* __restrict__ g,
                                   const float* __restrict__ be, float invN) {
    int c = threadIdx.x;
    if (c < 128) {
        float mu  = stats[c] * invN;
        float var = stats[c + 128] * invN - mu * mu;
        float sc  = g[c] * rsqrtf(var + BN_EPS);
        stats[c]       = sc;
        stats[c + 128] = be[c] - mu * sc;
    }
}

// ---------------- host launch ----------------
extern "C" void kernel_launch(void* const* d_in, const int* in_sizes, int n_in,
                              void* d_out, int out_size, void* d_ws, size_t ws_size,
                              hipStream_t stream) {
    const float* x   = (const float*)d_in[0];
    const void*  eix = d_in[1];
    const float* W1  = (const float*)d_in[2];
    const float* b1  = (const float*)d_in[3];
    const float* g1  = (const float*)d_in[4];
    const float* be1 = (const float*)d_in[5];
    const float* W2  = (const float*)d_in[6];
    const float* b2  = (const float*)d_in[7];
    const float* g2  = (const float*)d_in[8];
    const float* be2 = (const float*)d_in[9];
    const float* W3  = (const float*)d_in[10];
    const float* b3  = (const float*)d_in[11];
    float* outp = (float*)d_out;

    const int N = in_sizes[0] / 128;
    const int E = in_sizes[1] / 2;

    char* base = (char*)d_ws;
    size_t off = 0;
    auto alloc = [&](size_t bytes) -> char* {
        char* p = base + off;
        off = (off + bytes + 255) & ~(size_t)255;
        return p;
    };
    __hip_bfloat16* A = (__hip_bfloat16*)alloc((size_t)N * 128 * 2); // hw (bf16)
    float* B          = (float*)alloc((size_t)N * 128 * 4);          // pre-BN h (f32)
    int*   cnt        = (int*)alloc((size_t)N * 4);
    int*   rp         = (int*)alloc((size_t)(N + 1) * 4);
    int*   cursor     = (int*)alloc((size_t)N * 4);
    float* dis        = (float*)alloc((size_t)N * 4);
    int2*  ep         = (int2*)alloc((size_t)E * 8);
    int*   bsum       = (int*)alloc(4096);
    float* stats1     = (float*)alloc(256 * 4);
    float* stats2     = (float*)alloc(256 * 4);
    int*   flag       = (int*)alloc(64);
    (void)ws_size; (void)n_in; (void)out_size;

    const int SB = (N + 255) / 256;

    // ---- graph preprocessing ----
    hipMemsetAsync(cnt, 0, (size_t)N * 4, stream);
    detect_kernel<<<1, 64, 0, stream>>>((const int*)eix, flag);
    count_deg_kernel<<<(E + 255) / 256, 256, 0, stream>>>(eix, flag, cnt, E);
    dis_kernel<<<(N + 255) / 256, 256, 0, stream>>>(cnt, dis, N);
    scan_partial_kernel<<<SB, 256, 0, stream>>>(cnt, rp, bsum, N);
    scan_blocks_kernel<<<1, 512, 0, stream>>>(bsum, SB);
    scan_add_kernel<<<SB, 256, 0, stream>>>(rp, cursor, cnt, bsum, N);
    fill_kernel<<<(E + 255) / 256, 256, 0, stream>>>(eix, flag, dis, cursor, ep, E);

    const float invN = 1.0f / (float)N;
    const int gemm128_grid = (N + 31) / 32;
    const int gemm64_grid  = (N + 63) / 64;
    const int agg128_grid  = (int)(((long long)N * 64 + 255) / 256);
    const int agg64_grid   = (int)(((long long)N * 32 + 255) / 256);

    // ---- layer 1 ----
    gemm_kernel<128, false><<<gemm128_grid, 256, 0, stream>>>(x, W1, nullptr, A, N);
    agg_kernel<128><<<agg128_grid, 256, 0, stream>>>(A, rp, ep, dis, b1, B, N);
    hipMemsetAsync(stats1, 0, 256 * 4, stream);
    bn_stats_kernel<<<256, 256, 0, stream>>>(B, stats1, N);
    bn_finalize_kernel<<<1, 128, 0, stream>>>(stats1, g1, be1, invN);

    // ---- layer 2 (BN+relu fused into gemm H-staging) ----
    gemm_kernel<128, true><<<gemm128_grid, 256, 0, stream>>>(B, W2, stats1, A, N);
    agg_kernel<128><<<agg128_grid, 256, 0, stream>>>(A, rp, ep, dis, b2, B, N);
    hipMemsetAsync(stats2, 0, 256 * 4, stream);
    bn_stats_kernel<<<256, 256, 0, stream>>>(B, stats2, N);
    bn_finalize_kernel<<<1, 128, 0, stream>>>(stats2, g2, be2, invN);

    // ---- layer 3 (BN+relu fused; no BN after) ----
    gemm_kernel<64, true><<<gemm64_grid, 256, 0, stream>>>(B, W3, stats2, A, N);
    agg_kernel<64><<<agg64_grid, 256, 0, stream>>>(A, rp, ep, dis, b3, outp, N);
}

// Round 3
// 623.250 us; speedup vs baseline: 1.4170x; 1.0083x over previous
//
#include <hip/hip_runtime.h>
#include <hip/hip_bf16.h>

#define BN_EPS 1e-5f
#define BINSH 9
#define MAXNB 200

__device__ __forceinline__ float u2f(unsigned x) { return __uint_as_float(x); }
__device__ __forceinline__ unsigned short f2bf(float f) {
    union { __hip_bfloat16 h; unsigned short u; } cv;
    cv.h = __float2bfloat16(f);
    return cv.u;
}

// ---------------- edge dtype detection ----------------
__global__ void detect_kernel(const int* __restrict__ e32, int* __restrict__ flag) {
    if (threadIdx.x == 0 && blockIdx.x == 0) {
        int nz = 0;
        for (int i = 0; i < 64; ++i) nz += (e32[2*i + 1] != 0);
        *flag = (nz == 0) ? 1 : 0;
    }
}

__device__ __forceinline__ int edge_at(const void* p, long long i, int is64) {
    return is64 ? (int)((const long long*)p)[i] : ((const int*)p)[i];
}

// ---------------- degree count ----------------
__global__ void count_deg_kernel(const void* __restrict__ eidx, const int* __restrict__ flag,
                                 int* __restrict__ cnt, int E) {
    int e = blockIdx.x * blockDim.x + threadIdx.x;
    if (e >= E) return;
    int is64 = *flag;
    int d = edge_at(eidx, (long long)E + e, is64);
    atomicAdd(&cnt[d], 1);
}

// ---------------- prefix scan (3-phase) ----------------
__global__ void scan_partial_kernel(const int* __restrict__ cnt, int* __restrict__ rp,
                                    int* __restrict__ bsum, int n) {
    __shared__ int s[256];
    const int t = threadIdx.x;
    const int i = blockIdx.x * 256 + t;
    int v = (i < n) ? cnt[i] : 0;
    s[t] = v;
    __syncthreads();
    for (int off = 1; off < 256; off <<= 1) {
        int x = (t >= off) ? s[t - off] : 0;
        __syncthreads();
        s[t] += x;
        __syncthreads();
    }
    if (i < n) rp[i + 1] = s[t];
    if (t == 255) bsum[blockIdx.x] = s[255];
}

__global__ void scan_blocks_kernel(int* __restrict__ bs, int nb) {
    __shared__ int s[512];
    __shared__ int carry_s;
    const int t = threadIdx.x;
    if (t == 0) carry_s = 0;
    __syncthreads();
    for (int base = 0; base < nb; base += 512) {
        int v = (base + t < nb) ? bs[base + t] : 0;
        s[t] = v;
        __syncthreads();
        for (int off = 1; off < 512; off <<= 1) {
            int x = (t >= off) ? s[t - off] : 0;
            __syncthreads();
            s[t] += x;
            __syncthreads();
        }
        int inc = s[t];
        int total = s[511];
        int carry = carry_s;
        __syncthreads();
        if (base + t < nb) bs[base + t] = inc - v + carry;
        if (t == 0) carry_s = carry + total;
        __syncthreads();
    }
}

// rp finalize + dis
__global__ void scan_add_kernel(int* __restrict__ rp, const int* __restrict__ cnt,
                                const int* __restrict__ bsum, float* __restrict__ dis, int n) {
    int i = blockIdx.x * 256 + threadIdx.x;
    if (i < n) {
        int off = bsum[blockIdx.x];
        rp[i + 1] += off;
        dis[i] = rsqrtf((float)cnt[i] + 1.0f);
    }
    if (i == 0) rp[0] = 0;
}

// ---------------- bin prep: padded bin starts from rp ----------------
__global__ void binprep_kernel(const int* __restrict__ rp, int* __restrict__ binrp,
                               int* __restrict__ gcur, int N, int NB) {
    __shared__ int s[256];
    const int t = threadIdx.x;
    int pad = 0;
    if (t < NB) {
        int d0 = t << BINSH;
        int d1 = min(d0 + (1 << BINSH), N);
        int bh = rp[d1] - rp[d0];
        pad = (bh + 7) & ~7;
    }
    s[t] = pad;
    __syncthreads();
    for (int off = 1; off < 256; off <<= 1) {
        int x = (t >= off) ? s[t - off] : 0;
        __syncthreads();
        s[t] += x;
        __syncthreads();
    }
    if (t < NB) {
        int start = s[t] - pad;
        binrp[t] = start;
        gcur[t]  = start;
    }
}

// ---------------- pass 1: binned scatter with LDS ring staging ----------------
__global__ __launch_bounds__(256) void binscat_kernel(const void* __restrict__ eidx,
                                                      const int* __restrict__ flag,
                                                      int* __restrict__ gcur,
                                                      int2* __restrict__ ibuf,
                                                      int E, int NB, int per_block) {
    __shared__ int2 stag[MAXNB][32];
    __shared__ int scnt[MAXNB], sfl[MAXNB];
    const int t = threadIdx.x;
    if (t < NB) { scnt[t] = 0; sfl[t] = 0; }
    __syncthreads();
    const int is64 = *flag;
    long long base = (long long)blockIdx.x * per_block;
    long long lim = base + per_block;
    if (lim > E) lim = E;
    for (long long off = base; off < lim; off += 256) {
        long long e = off + t;
        if (e < lim) {
            int s = edge_at(eidx, e, is64);
            int d = edge_at(eidx, (long long)E + e, is64);
            int b = d >> BINSH;
            int k = atomicAdd(&scnt[b], 1);
            stag[b][k & 31] = make_int2(s, d);
        }
        __syncthreads();
        if (t < NB) {
            while (scnt[t] - sfl[t] >= 8) {
                int pos = atomicAdd(&gcur[t], 8);
                const int r = sfl[t] & 31;
                int4* dst = (int4*)(ibuf + pos);
                const int4* src = (const int4*)&stag[t][r];
                dst[0] = src[0]; dst[1] = src[1]; dst[2] = src[2]; dst[3] = src[3];
                sfl[t] += 8;
            }
        }
        __syncthreads();
    }
    if (t < NB) {
        int c = scnt[t], f = sfl[t];
        if (c > f) {
            int pos = atomicAdd(&gcur[t], c - f);
            for (; f < c; ++f, ++pos) ibuf[pos] = stag[t][f & 31];
        }
    }
}

// ---------------- pass 2: exact dst-sort within bin (block-private output) ----------------
__global__ __launch_bounds__(256) void binsort_kernel(const int2* __restrict__ ibuf,
                                                      const int* __restrict__ binrp,
                                                      const int* __restrict__ rp,
                                                      const float* __restrict__ dis,
                                                      int2* __restrict__ ep, int N) {
    const int b  = blockIdx.x;
    const int d0 = b << BINSH;
    const int dc = min(1 << BINSH, N - d0);
    __shared__ int   lrp[(1 << BINSH) + 1];
    __shared__ float sdis[1 << BINSH];
    __shared__ int   lcur[1 << BINSH];
    const int t = threadIdx.x;
    for (int i = t; i <= dc; i += 256) lrp[i] = rp[d0 + i];
    for (int i = t; i < dc; i += 256) { sdis[i] = dis[d0 + i]; lcur[i] = 0; }
    __syncthreads();
    const int nE  = lrp[dc] - lrp[0];
    const int ib0 = binrp[b];
    for (int i = t; i < nE; i += 256) {
        int2 sd = ibuf[ib0 + i];
        int dl = sd.y - d0;
        float w = dis[sd.x] * sdis[dl];
        int pos = lrp[dl] + atomicAdd(&lcur[dl], 1);
        ep[pos] = make_int2(sd.x, __float_as_int(w));
    }
}

// ---------------- GEMM: out[N][DOUT] = bnrelu(H)[N][128] @ W[128][DOUT], bf16 out ----------------
__device__ __forceinline__ float ldf(const float* p, size_t i) { return p[i]; }
__device__ __forceinline__ float ldf(const __hip_bfloat16* p, size_t i) { return __bfloat162float(p[i]); }

template <int DOUT, bool BN, typename TH>
__global__ __launch_bounds__(256) void gemm_kernel(const TH* __restrict__ H,
                                                   const float* __restrict__ W,
                                                   const float* __restrict__ bnst,
                                                   __hip_bfloat16* __restrict__ out, int N) {
    constexpr int ROWS = 4096 / DOUT;   // 32 (D=128) or 64 (D=64)
    constexpr int CG   = DOUT / 4;
    __shared__ float sW[64 * DOUT];
    __shared__ float sH[ROWS * 64];
    const int t   = threadIdx.x;
    const int cg  = t % CG;
    const int rg  = t / CG;
    const int row0 = blockIdx.x * ROWS;
    float acc[4][4] = {{0.f}};
    for (int kb = 0; kb < 128; kb += 64) {
        for (int i = t; i < 64 * DOUT / 4; i += 256)
            ((float4*)sW)[i] = ((const float4*)(W + (size_t)kb * DOUT))[i];
        {
            const int r = t >> 6, l = t & 63;
            float sc = 1.f, sh = 0.f;
            if (BN) { sc = bnst[kb + l]; sh = bnst[128 + kb + l]; }
            for (int rr = r; rr < ROWS; rr += 4) {
                int grow = row0 + rr;
                float v = (grow < N) ? ldf(H, (size_t)grow * 128 + kb + l) : 0.f;
                if (BN) v = fmaxf(v * sc + sh, 0.f);
                sH[rr * 64 + l] = v;
            }
        }
        __syncthreads();
#pragma unroll 8
        for (int k = 0; k < 64; ++k) {
            const float4 wv = *(const float4*)(&sW[k * DOUT + cg * 4]);
            float hv[4];
#pragma unroll
            for (int i = 0; i < 4; ++i) hv[i] = sH[(rg * 4 + i) * 64 + k];
#pragma unroll
            for (int i = 0; i < 4; ++i) {
                acc[i][0] += hv[i] * wv.x;
                acc[i][1] += hv[i] * wv.y;
                acc[i][2] += hv[i] * wv.z;
                acc[i][3] += hv[i] * wv.w;
            }
        }
        __syncthreads();
    }
#pragma unroll
    for (int i = 0; i < 4; ++i) {
        int grow = row0 + rg * 4 + i;
        if (grow < N) {
            __hip_bfloat16* op = out + (size_t)grow * DOUT + cg * 4;
            __hip_bfloat162 p0, p1;
            p0.x = __float2bfloat16(acc[i][0]);
            p0.y = __float2bfloat16(acc[i][1]);
            p1.x = __float2bfloat16(acc[i][2]);
            p1.y = __float2bfloat16(acc[i][3]);
            ((__hip_bfloat162*)op)[0] = p0;
            ((__hip_bfloat162*)op)[1] = p1;
        }
    }
}

// ---------------- aggregation: 4 cols/thread, 4x edge unroll ----------------
template <int D, bool OUTBF>
__global__ void agg_kernel(const __hip_bfloat16* __restrict__ hw, const int* __restrict__ rp,
                           const int2* __restrict__ ep, const float* __restrict__ dis,
                           const float* __restrict__ bias, void* __restrict__ outv, int N) {
    constexpr int LPR = D / 4;          // threads per row, 4 cols each
    int gtid = blockIdx.x * blockDim.x + threadIdx.x;
    int n    = gtid / LPR;
    int lane = gtid % LPR;
    if (n >= N) return;
    const uint2* hw4 = (const uint2*)hw;
    float sn = dis[n];
    sn *= sn;
    uint2 hv = hw4[(size_t)n * LPR + lane];
    float a0 = u2f(hv.x << 16) * sn;
    float a1 = u2f(hv.x & 0xffff0000u) * sn;
    float a2 = u2f(hv.y << 16) * sn;
    float a3 = u2f(hv.y & 0xffff0000u) * sn;
    int e0 = rp[n], e1 = rp[n + 1];
    int e = e0;
    for (; e + 4 <= e1; e += 4) {
        int2 p0 = ep[e + 0];
        int2 p1 = ep[e + 1];
        int2 p2 = ep[e + 2];
        int2 p3 = ep[e + 3];
        uint2 v0 = hw4[(size_t)p0.x * LPR + lane];
        uint2 v1 = hw4[(size_t)p1.x * LPR + lane];
        uint2 v2 = hw4[(size_t)p2.x * LPR + lane];
        uint2 v3 = hw4[(size_t)p3.x * LPR + lane];
        float w0 = __int_as_float(p0.y), w1 = __int_as_float(p1.y);
        float w2 = __int_as_float(p2.y), w3 = __int_as_float(p3.y);
        a0 += u2f(v0.x << 16) * w0; a1 += u2f(v0.x & 0xffff0000u) * w0;
        a2 += u2f(v0.y << 16) * w0; a3 += u2f(v0.y & 0xffff0000u) * w0;
        a0 += u2f(v1.x << 16) * w1; a1 += u2f(v1.x & 0xffff0000u) * w1;
        a2 += u2f(v1.y << 16) * w1; a3 += u2f(v1.y & 0xffff0000u) * w1;
        a0 += u2f(v2.x << 16) * w2; a1 += u2f(v2.x & 0xffff0000u) * w2;
        a2 += u2f(v2.y << 16) * w2; a3 += u2f(v2.y & 0xffff0000u) * w2;
        a0 += u2f(v3.x << 16) * w3; a1 += u2f(v3.x & 0xffff0000u) * w3;
        a2 += u2f(v3.y << 16) * w3; a3 += u2f(v3.y & 0xffff0000u) * w3;
    }
    for (; e < e1; ++e) {
        int2 p = ep[e];
        uint2 v = hw4[(size_t)p.x * LPR + lane];
        float w = __int_as_float(p.y);
        a0 += u2f(v.x << 16) * w; a1 += u2f(v.x & 0xffff0000u) * w;
        a2 += u2f(v.y << 16) * w; a3 += u2f(v.y & 0xffff0000u) * w;
    }
    float4 bv = ((const float4*)bias)[lane];
    a0 += bv.x; a1 += bv.y; a2 += bv.z; a3 += bv.w;
    if (OUTBF) {
        ushort4 o;
        o.x = f2bf(a0); o.y = f2bf(a1); o.z = f2bf(a2); o.w = f2bf(a3);
        ((ushort4*)outv)[(size_t)n * LPR + lane] = o;
    } else {
        ((float4*)outv)[(size_t)n * LPR + lane] = make_float4(a0, a1, a2, a3);
    }
}

// ---------------- batchnorm stats (bf16 input) ----------------
__global__ void bn_stats_kernel(const __hip_bfloat16* __restrict__ X, float* __restrict__ stats, int N) {
    const int t  = threadIdx.x;
    const int c4 = t & 31;      // cols 4c4..4c4+3
    const int rg = t >> 5;      // 0..7
    const uint2* X4 = (const uint2*)X;
    float s0=0,s1=0,s2=0,s3=0,q0=0,q1=0,q2=0,q3=0;
    for (int r = blockIdx.x * 8 + rg; r < N; r += gridDim.x * 8) {
        uint2 v = X4[(size_t)r * 32 + c4];
        float f0 = u2f(v.x << 16), f1 = u2f(v.x & 0xffff0000u);
        float f2 = u2f(v.y << 16), f3 = u2f(v.y & 0xffff0000u);
        s0 += f0; q0 += f0 * f0;
        s1 += f1; q1 += f1 * f1;
        s2 += f2; q2 += f2 * f2;
        s3 += f3; q3 += f3 * f3;
    }
    __shared__ float ls[8][32][8];
    ls[rg][c4][0] = s0; ls[rg][c4][1] = s1; ls[rg][c4][2] = s2; ls[rg][c4][3] = s3;
    ls[rg][c4][4] = q0; ls[rg][c4][5] = q1; ls[rg][c4][6] = q2; ls[rg][c4][7] = q3;
    __syncthreads();
    if (t < 32) {
        float a[8] = {0,0,0,0,0,0,0,0};
        for (int g = 0; g < 8; ++g)
            for (int k = 0; k < 8; ++k) a[k] += ls[g][t][k];
        for (int k = 0; k < 4; ++k) {
            atomicAdd(&stats[t * 4 + k], a[k]);
            atomicAdd(&stats[128 + t * 4 + k], a[4 + k]);
        }
    }
}

__global__ void bn_finalize_kernel(float* __restrict__ stats, const float* __restrict__ g,
                                   const float* __restrict__ be, float invN) {
    int c = threadIdx.x;
    if (c < 128) {
        float mu  = stats[c] * invN;
        float var = stats[c + 128] * invN - mu * mu;
        float sc  = g[c] * rsqrtf(var + BN_EPS);
        stats[c]       = sc;
        stats[c + 128] = be[c] - mu * sc;
    }
}

// ---------------- host launch ----------------
extern "C" void kernel_launch(void* const* d_in, const int* in_sizes, int n_in,
                              void* d_out, int out_size, void* d_ws, size_t ws_size,
                              hipStream_t stream) {
    const float* x   = (const float*)d_in[0];
    const void*  eix = d_in[1];
    const float* W1  = (const float*)d_in[2];
    const float* b1  = (const float*)d_in[3];
    const float* g1  = (const float*)d_in[4];
    const float* be1 = (const float*)d_in[5];
    const float* W2  = (const float*)d_in[6];
    const float* b2  = (const float*)d_in[7];
    const float* g2  = (const float*)d_in[8];
    const float* be2 = (const float*)d_in[9];
    const float* W3  = (const float*)d_in[10];
    const float* b3  = (const float*)d_in[11];
    float* outp = (float*)d_out;

    const int N = in_sizes[0] / 128;
    const int E = in_sizes[1] / 2;
    const int NB = (N + (1 << BINSH) - 1) >> BINSH;   // 196 for N=100000

    char* base = (char*)d_ws;
    size_t off = 0;
    auto alloc = [&](size_t bytes) -> char* {
        char* p = base + off;
        off = (off + bytes + 255) & ~(size_t)255;
        return p;
    };
    __hip_bfloat16* A = (__hip_bfloat16*)alloc((size_t)N * 128 * 2); // hw (bf16)
    __hip_bfloat16* B = (__hip_bfloat16*)alloc((size_t)N * 128 * 2); // pre-BN h (bf16)
    int*   cnt   = (int*)alloc((size_t)N * 4);
    int*   rp    = (int*)alloc((size_t)(N + 1) * 4);
    float* dis   = (float*)alloc((size_t)N * 4);
    int2*  ep    = (int2*)alloc((size_t)E * 8);
    int2*  ibuf  = (int2*)alloc(((size_t)E + MAXNB * 8) * 8);
    int*   binrp = (int*)alloc(MAXNB * 4);
    int*   gcur  = (int*)alloc(MAXNB * 4);
    int*   bsum  = (int*)alloc(4096);
    float* stats1 = (float*)alloc(256 * 4);
    float* stats2 = (float*)alloc(256 * 4);
    int*   flag  = (int*)alloc(64);
    (void)ws_size; (void)n_in; (void)out_size;

    const int SB = (N + 255) / 256;

    // ---- graph preprocessing ----
    hipMemsetAsync(cnt, 0, (size_t)N * 4, stream);
    detect_kernel<<<1, 64, 0, stream>>>((const int*)eix, flag);
    count_deg_kernel<<<(E + 255) / 256, 256, 0, stream>>>(eix, flag, cnt, E);
    scan_partial_kernel<<<SB, 256, 0, stream>>>(cnt, rp, bsum, N);
    scan_blocks_kernel<<<1, 512, 0, stream>>>(bsum, SB);
    scan_add_kernel<<<SB, 256, 0, stream>>>(rp, cnt, bsum, dis, N);
    binprep_kernel<<<1, 256, 0, stream>>>(rp, binrp, gcur, N, NB);
    const int per_block = (E + 255) / 256;
    binscat_kernel<<<256, 256, 0, stream>>>(eix, flag, gcur, ibuf, E, NB, per_block);
    binsort_kernel<<<NB, 256, 0, stream>>>(ibuf, binrp, rp, dis, ep, N);

    const float invN = 1.0f / (float)N;
    const int gemm128_grid = (N + 31) / 32;
    const int gemm64_grid  = (N + 63) / 64;
    const int agg128_grid  = (int)(((long long)N * 32 + 255) / 256);
    const int agg64_grid   = (int)(((long long)N * 16 + 255) / 256);

    // ---- layer 1 ----
    gemm_kernel<128, false, float><<<gemm128_grid, 256, 0, stream>>>(x, W1, nullptr, A, N);
    agg_kernel<128, true><<<agg128_grid, 256, 0, stream>>>(A, rp, ep, dis, b1, B, N);
    hipMemsetAsync(stats1, 0, 256 * 4, stream);
    bn_stats_kernel<<<256, 256, 0, stream>>>(B, stats1, N);
    bn_finalize_kernel<<<1, 128, 0, stream>>>(stats1, g1, be1, invN);

    // ---- layer 2 ----
    gemm_kernel<128, true, __hip_bfloat16><<<gemm128_grid, 256, 0, stream>>>(B, W2, stats1, A, N);
    agg_kernel<128, true><<<agg128_grid, 256, 0, stream>>>(A, rp, ep, dis, b2, B, N);
    hipMemsetAsync(stats2, 0, 256 * 4, stream);
    bn_stats_kernel<<<256, 256, 0, stream>>>(B, stats2, N);
    bn_finalize_kernel<<<1, 128, 0, stream>>>(stats2, g2, be2, invN);

    // ---- layer 3 ----
    gemm_kernel<64, true, __hip_bfloat16><<<gemm64_grid, 256, 0, stream>>>(B, W3, stats2, A, N);
    agg_kernel<64, false><<<agg64_grid, 256, 0, stream>>>(A, rp, ep, dis, b3, outp, N);
}

// Round 4
// 536.909 us; speedup vs baseline: 1.6449x; 1.1608x over previous
//
#include <hip/hip_runtime.h>
#include <hip/hip_bf16.h>

#define BN_EPS 1e-5f
#define BINSH 9
#define MAXNB 200
#define NBLK 256

__device__ __forceinline__ float u2f(unsigned x) { return __uint_as_float(x); }
__device__ __forceinline__ unsigned short f2bf(float f) {
    union { __hip_bfloat16 h; unsigned short u; } cv;
    cv.h = __float2bfloat16(f);
    return cv.u;
}

// ---------------- edge dtype detection ----------------
__global__ void detect_kernel(const int* __restrict__ e32, int* __restrict__ flag) {
    if (threadIdx.x == 0 && blockIdx.x == 0) {
        int nz = 0;
        for (int i = 0; i < 64; ++i) nz += (e32[2*i + 1] != 0);
        *flag = (nz == 0) ? 1 : 0;
    }
}

__device__ __forceinline__ int edge_at(const void* p, long long i, int is64) {
    return is64 ? (int)((const long long*)p)[i] : ((const int*)p)[i];
}

// ---------------- pass A: per-block bin histogram ----------------
__global__ __launch_bounds__(256) void histA_kernel(const void* __restrict__ eidx,
                                                    const int* __restrict__ flag,
                                                    int* __restrict__ hist2d,
                                                    int* __restrict__ binhist,
                                                    int E, int NB, int per_block) {
    __shared__ int lh[MAXNB];
    const int t = threadIdx.x;
    for (int i = t; i < NB; i += 256) lh[i] = 0;
    __syncthreads();
    const int is64 = *flag;
    long long base = (long long)blockIdx.x * per_block;
    long long lim  = base + per_block;
    if (lim > E) lim = E;
    for (long long e = base + t; e < lim; e += 256) {
        int d = edge_at(eidx, (long long)E + e, is64);
        atomicAdd(&lh[d >> BINSH], 1);
    }
    __syncthreads();
    for (int i = t; i < NB; i += 256) {
        hist2d[blockIdx.x * MAXNB + i] = lh[i];
        atomicAdd(&binhist[i], lh[i]);
    }
}

// ---------------- scan: binrp (exact bin starts) + per-(block,bin) bases ----------------
__global__ void basescan_kernel(const int* __restrict__ binhist, int* __restrict__ binrp,
                                int* __restrict__ hist2d, int NB, int nblk) {
    __shared__ int s[256];
    const int t = threadIdx.x;
    int v = (t < NB) ? binhist[t] : 0;
    s[t] = v;
    __syncthreads();
    for (int off = 1; off < 256; off <<= 1) {
        int x = (t >= off) ? s[t - off] : 0;
        __syncthreads();
        s[t] += x;
        __syncthreads();
    }
    int excl = s[t] - v;
    if (t < NB) binrp[t] = excl;
    if (t == 0) binrp[NB] = s[255];
    if (t < NB) {
        int run = excl;
        for (int blk = 0; blk < nblk; ++blk) {
            int c = hist2d[blk * MAXNB + t];
            hist2d[blk * MAXNB + t] = run;
            run += c;
        }
    }
}

// ---------------- pass B: edge-parallel scatter into reserved ranges ----------------
__global__ __launch_bounds__(256) void passB_kernel(const void* __restrict__ eidx,
                                                    const int* __restrict__ flag,
                                                    const int* __restrict__ hist2d,
                                                    int2* __restrict__ ibuf,
                                                    int E, int NB, int per_block) {
    __shared__ int lbase[MAXNB];
    __shared__ int lcur[MAXNB];
    const int t = threadIdx.x;
    for (int i = t; i < NB; i += 256) {
        lbase[i] = hist2d[blockIdx.x * MAXNB + i];
        lcur[i]  = 0;
    }
    __syncthreads();
    const int is64 = *flag;
    long long base = (long long)blockIdx.x * per_block;
    long long lim  = base + per_block;
    if (lim > E) lim = E;
    for (long long e = base + t; e < lim; e += 256) {
        int sN = edge_at(eidx, e, is64);
        int d  = edge_at(eidx, (long long)E + e, is64);
        int b  = d >> BINSH;
        int pos = lbase[b] + atomicAdd(&lcur[b], 1);
        ibuf[pos] = make_int2(sN, d);
    }
}

// ---------------- per-bin exact sort; computes rp + dis as a side effect ----------------
__global__ __launch_bounds__(256) void binsort2_kernel(const int2* __restrict__ ibuf,
                                                       const int* __restrict__ binrp,
                                                       int* __restrict__ rp,
                                                       float* __restrict__ dis,
                                                       int2* __restrict__ ep, int N) {
    const int b  = blockIdx.x;
    const int d0 = b << BINSH;
    const int dc = min(1 << BINSH, N - d0);
    __shared__ int lcnt[1 << BINSH];
    __shared__ int lofs[1 << BINSH];
    __shared__ int s2[256];
    const int t = threadIdx.x;
    lcnt[t] = 0; lcnt[t + 256] = 0;
    __syncthreads();
    const int ib0 = binrp[b], ib1 = binrp[b + 1];
    const int nE  = ib1 - ib0;
    for (int i = t; i < nE; i += 256) {
        int2 sd = ibuf[ib0 + i];
        atomicAdd(&lcnt[sd.y - d0], 1);
    }
    __syncthreads();
    // scan of 512 counters with 256 threads (pairwise)
    const int c0 = lcnt[2 * t], c1 = lcnt[2 * t + 1];
    const int pair = c0 + c1;
    s2[t] = pair;
    __syncthreads();
    for (int off = 1; off < 256; off <<= 1) {
        int x = (t >= off) ? s2[t - off] : 0;
        __syncthreads();
        s2[t] += x;
        __syncthreads();
    }
    const int pexcl = s2[t] - pair;
    // rp and dis
    if (2 * t < dc) {
        rp[d0 + 2 * t + 1] = ib0 + pexcl + c0;
        dis[d0 + 2 * t]    = rsqrtf((float)c0 + 1.0f);
    }
    if (2 * t + 1 < dc) {
        rp[d0 + 2 * t + 2] = ib0 + pexcl + pair;
        dis[d0 + 2 * t + 1] = rsqrtf((float)c1 + 1.0f);
    }
    if (b == 0 && t == 0) rp[0] = 0;
    lofs[2 * t]     = pexcl;
    lofs[2 * t + 1] = pexcl + c0;
    __syncthreads();
    // place
    for (int i = t; i < nE; i += 256) {
        int2 sd = ibuf[ib0 + i];
        int dl  = sd.y - d0;
        int pos = ib0 + atomicAdd(&lofs[dl], 1);
        ep[pos] = sd;
    }
}

// ---------------- weights: (src,dst) -> (src,w) in place ----------------
__global__ void weight_kernel(int2* __restrict__ ep, const float* __restrict__ dis, int E) {
    int e = blockIdx.x * 256 + threadIdx.x;
    if (e >= E) return;
    int2 sd = ep[e];
    float w = dis[sd.x] * dis[sd.y];
    ep[e] = make_int2(sd.x, __float_as_int(w));
}

// ---------------- GEMM: out[N][DOUT] = bnrelu(H)[N][128] @ W[128][DOUT], bf16 out ----------------
__device__ __forceinline__ float ldf(const float* p, size_t i) { return p[i]; }
__device__ __forceinline__ float ldf(const __hip_bfloat16* p, size_t i) { return __bfloat162float(p[i]); }

template <int DOUT, bool BN, typename TH>
__global__ __launch_bounds__(256) void gemm_kernel(const TH* __restrict__ H,
                                                   const float* __restrict__ W,
                                                   const float* __restrict__ bnst,
                                                   __hip_bfloat16* __restrict__ out, int N) {
    constexpr int ROWS = 4096 / DOUT;   // 32 (D=128) or 64 (D=64)
    constexpr int CG   = DOUT / 4;
    __shared__ float sW[64 * DOUT];
    __shared__ float sH[ROWS * 64];
    const int t   = threadIdx.x;
    const int cg  = t % CG;
    const int rg  = t / CG;
    const int row0 = blockIdx.x * ROWS;
    float acc[4][4] = {{0.f}};
    for (int kb = 0; kb < 128; kb += 64) {
        for (int i = t; i < 64 * DOUT / 4; i += 256)
            ((float4*)sW)[i] = ((const float4*)(W + (size_t)kb * DOUT))[i];
        {
            const int r = t >> 6, l = t & 63;
            float sc = 1.f, sh = 0.f;
            if (BN) { sc = bnst[kb + l]; sh = bnst[128 + kb + l]; }
            for (int rr = r; rr < ROWS; rr += 4) {
                int grow = row0 + rr;
                float v = (grow < N) ? ldf(H, (size_t)grow * 128 + kb + l) : 0.f;
                if (BN) v = fmaxf(v * sc + sh, 0.f);
                sH[rr * 64 + l] = v;
            }
        }
        __syncthreads();
#pragma unroll 8
        for (int k = 0; k < 64; ++k) {
            const float4 wv = *(const float4*)(&sW[k * DOUT + cg * 4]);
            float hv[4];
#pragma unroll
            for (int i = 0; i < 4; ++i) hv[i] = sH[(rg * 4 + i) * 64 + k];
#pragma unroll
            for (int i = 0; i < 4; ++i) {
                acc[i][0] += hv[i] * wv.x;
                acc[i][1] += hv[i] * wv.y;
                acc[i][2] += hv[i] * wv.z;
                acc[i][3] += hv[i] * wv.w;
            }
        }
        __syncthreads();
    }
#pragma unroll
    for (int i = 0; i < 4; ++i) {
        int grow = row0 + rg * 4 + i;
        if (grow < N) {
            __hip_bfloat16* op = out + (size_t)grow * DOUT + cg * 4;
            __hip_bfloat162 p0, p1;
            p0.x = __float2bfloat16(acc[i][0]);
            p0.y = __float2bfloat16(acc[i][1]);
            p1.x = __float2bfloat16(acc[i][2]);
            p1.y = __float2bfloat16(acc[i][3]);
            ((__hip_bfloat162*)op)[0] = p0;
            ((__hip_bfloat162*)op)[1] = p1;
        }
    }
}

// ---------------- aggregation: 4 cols/thread, 4x edge unroll ----------------
template <int D, bool OUTBF>
__global__ void agg_kernel(const __hip_bfloat16* __restrict__ hw, const int* __restrict__ rp,
                           const int2* __restrict__ ep, const float* __restrict__ dis,
                           const float* __restrict__ bias, void* __restrict__ outv, int N) {
    constexpr int LPR = D / 4;          // threads per row, 4 cols each
    int gtid = blockIdx.x * blockDim.x + threadIdx.x;
    int n    = gtid / LPR;
    int lane = gtid % LPR;
    if (n >= N) return;
    const uint2* hw4 = (const uint2*)hw;
    float sn = dis[n];
    sn *= sn;
    uint2 hv = hw4[(size_t)n * LPR + lane];
    float a0 = u2f(hv.x << 16) * sn;
    float a1 = u2f(hv.x & 0xffff0000u) * sn;
    float a2 = u2f(hv.y << 16) * sn;
    float a3 = u2f(hv.y & 0xffff0000u) * sn;
    int e0 = rp[n], e1 = rp[n + 1];
    int e = e0;
    for (; e + 4 <= e1; e += 4) {
        int2 p0 = ep[e + 0];
        int2 p1 = ep[e + 1];
        int2 p2 = ep[e + 2];
        int2 p3 = ep[e + 3];
        uint2 v0 = hw4[(size_t)p0.x * LPR + lane];
        uint2 v1 = hw4[(size_t)p1.x * LPR + lane];
        uint2 v2 = hw4[(size_t)p2.x * LPR + lane];
        uint2 v3 = hw4[(size_t)p3.x * LPR + lane];
        float w0 = __int_as_float(p0.y), w1 = __int_as_float(p1.y);
        float w2 = __int_as_float(p2.y), w3 = __int_as_float(p3.y);
        a0 += u2f(v0.x << 16) * w0; a1 += u2f(v0.x & 0xffff0000u) * w0;
        a2 += u2f(v0.y << 16) * w0; a3 += u2f(v0.y & 0xffff0000u) * w0;
        a0 += u2f(v1.x << 16) * w1; a1 += u2f(v1.x & 0xffff0000u) * w1;
        a2 += u2f(v1.y << 16) * w1; a3 += u2f(v1.y & 0xffff0000u) * w1;
        a0 += u2f(v2.x << 16) * w2; a1 += u2f(v2.x & 0xffff0000u) * w2;
        a2 += u2f(v2.y << 16) * w2; a3 += u2f(v2.y & 0xffff0000u) * w2;
        a0 += u2f(v3.x << 16) * w3; a1 += u2f(v3.x & 0xffff0000u) * w3;
        a2 += u2f(v3.y << 16) * w3; a3 += u2f(v3.y & 0xffff0000u) * w3;
    }
    for (; e < e1; ++e) {
        int2 p = ep[e];
        uint2 v = hw4[(size_t)p.x * LPR + lane];
        float w = __int_as_float(p.y);
        a0 += u2f(v.x << 16) * w; a1 += u2f(v.x & 0xffff0000u) * w;
        a2 += u2f(v.y << 16) * w; a3 += u2f(v.y & 0xffff0000u) * w;
    }
    float4 bv = ((const float4*)bias)[lane];
    a0 += bv.x; a1 += bv.y; a2 += bv.z; a3 += bv.w;
    if (OUTBF) {
        ushort4 o;
        o.x = f2bf(a0); o.y = f2bf(a1); o.z = f2bf(a2); o.w = f2bf(a3);
        ((ushort4*)outv)[(size_t)n * LPR + lane] = o;
    } else {
        ((float4*)outv)[(size_t)n * LPR + lane] = make_float4(a0, a1, a2, a3);
    }
}

// ---------------- batchnorm stats (bf16 input) ----------------
__global__ void bn_stats_kernel(const __hip_bfloat16* __restrict__ X, float* __restrict__ stats, int N) {
    const int t  = threadIdx.x;
    const int c4 = t & 31;
    const int rg = t >> 5;
    const uint2* X4 = (const uint2*)X;
    float s0=0,s1=0,s2=0,s3=0,q0=0,q1=0,q2=0,q3=0;
    for (int r = blockIdx.x * 8 + rg; r < N; r += gridDim.x * 8) {
        uint2 v = X4[(size_t)r * 32 + c4];
        float f0 = u2f(v.x << 16), f1 = u2f(v.x & 0xffff0000u);
        float f2 = u2f(v.y << 16), f3 = u2f(v.y & 0xffff0000u);
        s0 += f0; q0 += f0 * f0;
        s1 += f1; q1 += f1 * f1;
        s2 += f2; q2 += f2 * f2;
        s3 += f3; q3 += f3 * f3;
    }
    __shared__ float ls[8][32][8];
    ls[rg][c4][0] = s0; ls[rg][c4][1] = s1; ls[rg][c4][2] = s2; ls[rg][c4][3] = s3;
    ls[rg][c4][4] = q0; ls[rg][c4][5] = q1; ls[rg][c4][6] = q2; ls[rg][c4][7] = q3;
    __syncthreads();
    if (t < 32) {
        float a[8] = {0,0,0,0,0,0,0,0};
        for (int g = 0; g < 8; ++g)
            for (int k = 0; k < 8; ++k) a[k] += ls[g][t][k];
        for (int k = 0; k < 4; ++k) {
            atomicAdd(&stats[t * 4 + k], a[k]);
            atomicAdd(&stats[128 + t * 4 + k], a[4 + k]);
        }
    }
}

__global__ void bn_finalize_kernel(float* __restrict__ stats, const float* __restrict__ g,
                                   const float* __restrict__ be, float invN) {
    int c = threadIdx.x;
    if (c < 128) {
        float mu  = stats[c] * invN;
        float var = stats[c + 128] * invN - mu * mu;
        float sc  = g[c] * rsqrtf(var + BN_EPS);
        stats[c]       = sc;
        stats[c + 128] = be[c] - mu * sc;
    }
}

// ---------------- host launch ----------------
extern "C" void kernel_launch(void* const* d_in, const int* in_sizes, int n_in,
                              void* d_out, int out_size, void* d_ws, size_t ws_size,
                              hipStream_t stream) {
    const float* x   = (const float*)d_in[0];
    const void*  eix = d_in[1];
    const float* W1  = (const float*)d_in[2];
    const float* b1  = (const float*)d_in[3];
    const float* g1  = (const float*)d_in[4];
    const float* be1 = (const float*)d_in[5];
    const float* W2  = (const float*)d_in[6];
    const float* b2  = (const float*)d_in[7];
    const float* g2  = (const float*)d_in[8];
    const float* be2 = (const float*)d_in[9];
    const float* W3  = (const float*)d_in[10];
    const float* b3  = (const float*)d_in[11];
    float* outp = (float*)d_out;

    const int N = in_sizes[0] / 128;
    const int E = in_sizes[1] / 2;
    const int NB = (N + (1 << BINSH) - 1) >> BINSH;   // 196 for N=100000

    char* base = (char*)d_ws;
    size_t off = 0;
    auto alloc = [&](size_t bytes) -> char* {
        char* p = base + off;
        off = (off + bytes + 255) & ~(size_t)255;
        return p;
    };
    __hip_bfloat16* A = (__hip_bfloat16*)alloc((size_t)N * 128 * 2); // hw (bf16)
    __hip_bfloat16* B = (__hip_bfloat16*)alloc((size_t)N * 128 * 2); // pre-BN h (bf16)
    int*   rp     = (int*)alloc((size_t)(N + 1) * 4);
    float* dis    = (float*)alloc((size_t)N * 4);
    int2*  ep     = (int2*)alloc((size_t)E * 8);
    int2*  ibuf   = (int2*)alloc((size_t)E * 8);
    int*   hist2d = (int*)alloc((size_t)NBLK * MAXNB * 4);
    int*   binhist= (int*)alloc(MAXNB * 4);
    int*   binrp  = (int*)alloc((MAXNB + 1) * 4);
    float* stats1 = (float*)alloc(256 * 4);
    float* stats2 = (float*)alloc(256 * 4);
    int*   flag   = (int*)alloc(64);
    (void)ws_size; (void)n_in; (void)out_size;

    const int per_block = (E + NBLK - 1) / NBLK;

    // ---- graph preprocessing ----
    detect_kernel<<<1, 64, 0, stream>>>((const int*)eix, flag);
    hipMemsetAsync(binhist, 0, MAXNB * 4, stream);
    histA_kernel<<<NBLK, 256, 0, stream>>>(eix, flag, hist2d, binhist, E, NB, per_block);
    basescan_kernel<<<1, 256, 0, stream>>>(binhist, binrp, hist2d, NB, NBLK);
    passB_kernel<<<NBLK, 256, 0, stream>>>(eix, flag, hist2d, ibuf, E, NB, per_block);
    binsort2_kernel<<<NB, 256, 0, stream>>>(ibuf, binrp, rp, dis, ep, N);
    weight_kernel<<<(E + 255) / 256, 256, 0, stream>>>(ep, dis, E);

    const float invN = 1.0f / (float)N;
    const int gemm128_grid = (N + 31) / 32;
    const int gemm64_grid  = (N + 63) / 64;
    const int agg128_grid  = (int)(((long long)N * 32 + 255) / 256);
    const int agg64_grid   = (int)(((long long)N * 16 + 255) / 256);

    // ---- layer 1 ----
    gemm_kernel<128, false, float><<<gemm128_grid, 256, 0, stream>>>(x, W1, nullptr, A, N);
    agg_kernel<128, true><<<agg128_grid, 256, 0, stream>>>(A, rp, ep, dis, b1, B, N);
    hipMemsetAsync(stats1, 0, 256 * 4, stream);
    bn_stats_kernel<<<256, 256, 0, stream>>>(B, stats1, N);
    bn_finalize_kernel<<<1, 128, 0, stream>>>(stats1, g1, be1, invN);

    // ---- layer 2 ----
    gemm_kernel<128, true, __hip_bfloat16><<<gemm128_grid, 256, 0, stream>>>(B, W2, stats1, A, N);
    agg_kernel<128, true><<<agg128_grid, 256, 0, stream>>>(A, rp, ep, dis, b2, B, N);
    hipMemsetAsync(stats2, 0, 256 * 4, stream);
    bn_stats_kernel<<<256, 256, 0, stream>>>(B, stats2, N);
    bn_finalize_kernel<<<1, 128, 0, stream>>>(stats2, g2, be2, invN);

    // ---- layer 3 ----
    gemm_kernel<64, true, __hip_bfloat16><<<gemm64_grid, 256, 0, stream>>>(B, W3, stats2, A, N);
    agg_kernel<64, false><<<agg64_grid, 256, 0, stream>>>(A, rp, ep, dis, b3, outp, N);
}

// Round 5
// 438.296 us; speedup vs baseline: 2.0150x; 1.2250x over previous
//
#include <hip/hip_runtime.h>
#include <hip/hip_bf16.h>

#define BN_EPS 1e-5f
#define BINSH 9
#define MAXNB 200
#define NBLK 256

typedef __attribute__((ext_vector_type(8))) short bf16x8v;
typedef __attribute__((ext_vector_type(4))) float f32x4v;

__device__ __forceinline__ float u2f(unsigned x) { return __uint_as_float(x); }
__device__ __forceinline__ unsigned short f2bf(float f) {
    union { __hip_bfloat16 h; unsigned short u; } cv;
    cv.h = __float2bfloat16(f);
    return cv.u;
}

// ---------------- edge dtype detection ----------------
__global__ void detect_kernel(const int* __restrict__ e32, int* __restrict__ flag) {
    if (threadIdx.x == 0 && blockIdx.x == 0) {
        int nz = 0;
        for (int i = 0; i < 64; ++i) nz += (e32[2*i + 1] != 0);
        *flag = (nz == 0) ? 1 : 0;
    }
}

__device__ __forceinline__ int edge_at(const void* p, long long i, int is64) {
    return is64 ? (int)((const long long*)p)[i] : ((const int*)p)[i];
}

// ---------------- pass A: per-block bin histogram ----------------
__global__ __launch_bounds__(256) void histA_kernel(const void* __restrict__ eidx,
                                                    const int* __restrict__ flag,
                                                    int* __restrict__ hist2d,
                                                    int* __restrict__ binhist,
                                                    int E, int NB, int per_block) {
    __shared__ int lh[MAXNB];
    const int t = threadIdx.x;
    for (int i = t; i < NB; i += 256) lh[i] = 0;
    __syncthreads();
    const int is64 = *flag;
    long long base = (long long)blockIdx.x * per_block;
    long long lim  = base + per_block;
    if (lim > E) lim = E;
    for (long long e = base + t; e < lim; e += 256) {
        int d = edge_at(eidx, (long long)E + e, is64);
        atomicAdd(&lh[d >> BINSH], 1);
    }
    __syncthreads();
    for (int i = t; i < NB; i += 256) {
        hist2d[blockIdx.x * MAXNB + i] = lh[i];
        atomicAdd(&binhist[i], lh[i]);
    }
}

// ---------------- scan: binrp + per-(block,bin) bases ----------------
__global__ void basescan_kernel(const int* __restrict__ binhist, int* __restrict__ binrp,
                                int* __restrict__ hist2d, int NB, int nblk) {
    __shared__ int s[256];
    const int t = threadIdx.x;
    int v = (t < NB) ? binhist[t] : 0;
    s[t] = v;
    __syncthreads();
    for (int off = 1; off < 256; off <<= 1) {
        int x = (t >= off) ? s[t - off] : 0;
        __syncthreads();
        s[t] += x;
        __syncthreads();
    }
    int excl = s[t] - v;
    if (t < NB) binrp[t] = excl;
    if (t == 0) binrp[NB] = s[255];
    if (t < NB) {
        int run = excl;
        for (int blk = 0; blk < nblk; ++blk) {
            int c = hist2d[blk * MAXNB + t];
            hist2d[blk * MAXNB + t] = run;
            run += c;
        }
    }
}

// ---------------- pass B: edge-parallel scatter into reserved ranges ----------------
__global__ __launch_bounds__(256) void passB_kernel(const void* __restrict__ eidx,
                                                    const int* __restrict__ flag,
                                                    const int* __restrict__ hist2d,
                                                    int2* __restrict__ ibuf,
                                                    int E, int NB, int per_block) {
    __shared__ int lbase[MAXNB];
    __shared__ int lcur[MAXNB];
    const int t = threadIdx.x;
    for (int i = t; i < NB; i += 256) {
        lbase[i] = hist2d[blockIdx.x * MAXNB + i];
        lcur[i]  = 0;
    }
    __syncthreads();
    const int is64 = *flag;
    long long base = (long long)blockIdx.x * per_block;
    long long lim  = base + per_block;
    if (lim > E) lim = E;
    for (long long e = base + t; e < lim; e += 256) {
        int sN = edge_at(eidx, e, is64);
        int d  = edge_at(eidx, (long long)E + e, is64);
        int b  = d >> BINSH;
        int pos = lbase[b] + atomicAdd(&lcur[b], 1);
        ibuf[pos] = make_int2(sN, d);
    }
}

// ---------------- per-bin exact sort; computes rp + dis ----------------
__global__ __launch_bounds__(256) void binsort2_kernel(const int2* __restrict__ ibuf,
                                                       const int* __restrict__ binrp,
                                                       int* __restrict__ rp,
                                                       float* __restrict__ dis,
                                                       int2* __restrict__ ep, int N) {
    const int b  = blockIdx.x;
    const int d0 = b << BINSH;
    const int dc = min(1 << BINSH, N - d0);
    __shared__ int lcnt[1 << BINSH];
    __shared__ int lofs[1 << BINSH];
    __shared__ int s2[256];
    const int t = threadIdx.x;
    lcnt[t] = 0; lcnt[t + 256] = 0;
    __syncthreads();
    const int ib0 = binrp[b], ib1 = binrp[b + 1];
    const int nE  = ib1 - ib0;
    for (int i = t; i < nE; i += 256) {
        int2 sd = ibuf[ib0 + i];
        atomicAdd(&lcnt[sd.y - d0], 1);
    }
    __syncthreads();
    const int c0 = lcnt[2 * t], c1 = lcnt[2 * t + 1];
    const int pair = c0 + c1;
    s2[t] = pair;
    __syncthreads();
    for (int off = 1; off < 256; off <<= 1) {
        int x = (t >= off) ? s2[t - off] : 0;
        __syncthreads();
        s2[t] += x;
        __syncthreads();
    }
    const int pexcl = s2[t] - pair;
    if (2 * t < dc) {
        rp[d0 + 2 * t + 1] = ib0 + pexcl + c0;
        dis[d0 + 2 * t]    = rsqrtf((float)c0 + 1.0f);
    }
    if (2 * t + 1 < dc) {
        rp[d0 + 2 * t + 2] = ib0 + pexcl + pair;
        dis[d0 + 2 * t + 1] = rsqrtf((float)c1 + 1.0f);
    }
    if (b == 0 && t == 0) rp[0] = 0;
    lofs[2 * t]     = pexcl;
    lofs[2 * t + 1] = pexcl + c0;
    __syncthreads();
    for (int i = t; i < nE; i += 256) {
        int2 sd = ibuf[ib0 + i];
        int dl  = sd.y - d0;
        int pos = ib0 + atomicAdd(&lofs[dl], 1);
        ep[pos] = sd;
    }
}

// ---------------- weights: (src,dst) -> (src,w) in place ----------------
__global__ void weight_kernel(int2* __restrict__ ep, const float* __restrict__ dis, int E) {
    int e = blockIdx.x * 256 + threadIdx.x;
    if (e >= E) return;
    int2 sd = ep[e];
    float w = dis[sd.x] * dis[sd.y];
    ep[e] = make_int2(sd.x, __float_as_int(w));
}

// ---------------- W -> W^T bf16 prep ----------------
__global__ void prep_wt_kernel(const float* __restrict__ W, __hip_bfloat16* __restrict__ Wt,
                               int K, int DOUT) {
    int i = blockIdx.x * 256 + threadIdx.x;
    if (i < K * DOUT) {
        int k = i / DOUT, c = i % DOUT;
        Wt[c * K + k] = __float2bfloat16(W[i]);
    }
}

// ---------------- fragment loaders (8 k-values -> f32[8]) ----------------
__device__ __forceinline__ void load8(const float* p, float* f) {
    float4 v0 = ((const float4*)p)[0];
    float4 v1 = ((const float4*)p)[1];
    f[0] = v0.x; f[1] = v0.y; f[2] = v0.z; f[3] = v0.w;
    f[4] = v1.x; f[5] = v1.y; f[6] = v1.z; f[7] = v1.w;
}
__device__ __forceinline__ void load8(const __hip_bfloat16* p, float* f) {
    uint4 v = *(const uint4*)p;
    f[0] = u2f(v.x << 16); f[1] = u2f(v.x & 0xffff0000u);
    f[2] = u2f(v.y << 16); f[3] = u2f(v.y & 0xffff0000u);
    f[4] = u2f(v.z << 16); f[5] = u2f(v.z & 0xffff0000u);
    f[6] = u2f(v.w << 16); f[7] = u2f(v.w & 0xffff0000u);
}

// ---------------- MFMA GEMM: out[N][DOUT] = bnrelu(H)[N][128] @ W, bf16 out ----------------
// Wt: bf16 [DOUT][128] (pre-transposed). Block: 64 rows, 4 waves (16 rows each).
template <int DOUT, bool BN, typename TH>
__global__ __launch_bounds__(256) void mfma_gemm_kernel(const TH* __restrict__ H,
                                                        const __hip_bfloat16* __restrict__ Wt,
                                                        const float* __restrict__ bnst,
                                                        __hip_bfloat16* __restrict__ out, int N) {
    constexpr int NCT = DOUT / 16;         // col tiles
    constexpr int LDW = 136;               // padded row (bf16): 272 B -> 4-bank step
    __shared__ __hip_bfloat16 sWt[DOUT * LDW];
    const int t = threadIdx.x;
    // stage W^T (contiguous 16B chunks; LDS rows padded)
    for (int i = t; i < DOUT * 16; i += 256) {
        int row = i >> 4, seg = i & 15;
        *(uint4*)&sWt[row * LDW + seg * 8] = ((const uint4*)Wt)[i];
    }
    const int lane = t & 63, wid = t >> 6;
    const int kq = lane >> 4, mrow = lane & 15;
    const int grow = blockIdx.x * 64 + wid * 16 + mrow;
    const int lrow = min(grow, N - 1);
    // A fragments: 4 k-steps x 8 contiguous k, BN+relu fused
    bf16x8v afrag[4];
#pragma unroll
    for (int ks = 0; ks < 4; ++ks) {
        const int k0 = ks * 32 + kq * 8;
        float f[8];
        load8(H + (size_t)lrow * 128 + k0, f);
        if (BN) {
            float4 s0 = *(const float4*)(bnst + k0);
            float4 s1 = *(const float4*)(bnst + k0 + 4);
            float4 h0 = *(const float4*)(bnst + 128 + k0);
            float4 h1 = *(const float4*)(bnst + 128 + k0 + 4);
            f[0] = fmaxf(fmaf(f[0], s0.x, h0.x), 0.f);
            f[1] = fmaxf(fmaf(f[1], s0.y, h0.y), 0.f);
            f[2] = fmaxf(fmaf(f[2], s0.z, h0.z), 0.f);
            f[3] = fmaxf(fmaf(f[3], s0.w, h0.w), 0.f);
            f[4] = fmaxf(fmaf(f[4], s1.x, h1.x), 0.f);
            f[5] = fmaxf(fmaf(f[5], s1.y, h1.y), 0.f);
            f[6] = fmaxf(fmaf(f[6], s1.z, h1.z), 0.f);
            f[7] = fmaxf(fmaf(f[7], s1.w, h1.w), 0.f);
        }
        bf16x8v a;
#pragma unroll
        for (int j = 0; j < 8; ++j) a[j] = (short)f2bf(f[j]);
        afrag[ks] = a;
    }
    __syncthreads();
    f32x4v acc[NCT];
#pragma unroll
    for (int ct = 0; ct < NCT; ++ct) acc[ct] = (f32x4v){0.f, 0.f, 0.f, 0.f};
#pragma unroll
    for (int ct = 0; ct < NCT; ++ct) {
#pragma unroll
        for (int ks = 0; ks < 4; ++ks) {
            bf16x8v b = *(const bf16x8v*)&sWt[(ct * 16 + mrow) * LDW + ks * 32 + kq * 8];
            acc[ct] = __builtin_amdgcn_mfma_f32_16x16x32_bf16(afrag[ks], b, acc[ct], 0, 0, 0);
        }
    }
    // store: C row = kq*4+r, col = ct*16 + mrow
#pragma unroll
    for (int r = 0; r < 4; ++r) {
        int orow = blockIdx.x * 64 + wid * 16 + kq * 4 + r;
        if (orow < N) {
            __hip_bfloat16* op = out + (size_t)orow * DOUT + mrow;
#pragma unroll
            for (int ct = 0; ct < NCT; ++ct) {
                union { unsigned short u; __hip_bfloat16 h; } cv;
                cv.u = f2bf(acc[ct][r]);
                op[ct * 16] = cv.h;
            }
        }
    }
}

// ---------------- aggregation: 4 cols/thread, 4x edge unroll ----------------
template <int D, bool OUTBF>
__global__ void agg_kernel(const __hip_bfloat16* __restrict__ hw, const int* __restrict__ rp,
                           const int2* __restrict__ ep, const float* __restrict__ dis,
                           const float* __restrict__ bias, void* __restrict__ outv, int N) {
    constexpr int LPR = D / 4;
    int gtid = blockIdx.x * blockDim.x + threadIdx.x;
    int n    = gtid / LPR;
    int lane = gtid % LPR;
    if (n >= N) return;
    const uint2* hw4 = (const uint2*)hw;
    float sn = dis[n];
    sn *= sn;
    uint2 hv = hw4[(size_t)n * LPR + lane];
    float a0 = u2f(hv.x << 16) * sn;
    float a1 = u2f(hv.x & 0xffff0000u) * sn;
    float a2 = u2f(hv.y << 16) * sn;
    float a3 = u2f(hv.y & 0xffff0000u) * sn;
    int e0 = rp[n], e1 = rp[n + 1];
    int e = e0;
    for (; e + 4 <= e1; e += 4) {
        int2 p0 = ep[e + 0];
        int2 p1 = ep[e + 1];
        int2 p2 = ep[e + 2];
        int2 p3 = ep[e + 3];
        uint2 v0 = hw4[(size_t)p0.x * LPR + lane];
        uint2 v1 = hw4[(size_t)p1.x * LPR + lane];
        uint2 v2 = hw4[(size_t)p2.x * LPR + lane];
        uint2 v3 = hw4[(size_t)p3.x * LPR + lane];
        float w0 = __int_as_float(p0.y), w1 = __int_as_float(p1.y);
        float w2 = __int_as_float(p2.y), w3 = __int_as_float(p3.y);
        a0 += u2f(v0.x << 16) * w0; a1 += u2f(v0.x & 0xffff0000u) * w0;
        a2 += u2f(v0.y << 16) * w0; a3 += u2f(v0.y & 0xffff0000u) * w0;
        a0 += u2f(v1.x << 16) * w1; a1 += u2f(v1.x & 0xffff0000u) * w1;
        a2 += u2f(v1.y << 16) * w1; a3 += u2f(v1.y & 0xffff0000u) * w1;
        a0 += u2f(v2.x << 16) * w2; a1 += u2f(v2.x & 0xffff0000u) * w2;
        a2 += u2f(v2.y << 16) * w2; a3 += u2f(v2.y & 0xffff0000u) * w2;
        a0 += u2f(v3.x << 16) * w3; a1 += u2f(v3.x & 0xffff0000u) * w3;
        a2 += u2f(v3.y << 16) * w3; a3 += u2f(v3.y & 0xffff0000u) * w3;
    }
    for (; e < e1; ++e) {
        int2 p = ep[e];
        uint2 v = hw4[(size_t)p.x * LPR + lane];
        float w = __int_as_float(p.y);
        a0 += u2f(v.x << 16) * w; a1 += u2f(v.x & 0xffff0000u) * w;
        a2 += u2f(v.y << 16) * w; a3 += u2f(v.y & 0xffff0000u) * w;
    }
    float4 bv = ((const float4*)bias)[lane];
    a0 += bv.x; a1 += bv.y; a2 += bv.z; a3 += bv.w;
    if (OUTBF) {
        ushort4 o;
        o.x = f2bf(a0); o.y = f2bf(a1); o.z = f2bf(a2); o.w = f2bf(a3);
        ((ushort4*)outv)[(size_t)n * LPR + lane] = o;
    } else {
        ((float4*)outv)[(size_t)n * LPR + lane] = make_float4(a0, a1, a2, a3);
    }
}

// ---------------- batchnorm stats (bf16 input) ----------------
__global__ void bn_stats_kernel(const __hip_bfloat16* __restrict__ X, float* __restrict__ stats, int N) {
    const int t  = threadIdx.x;
    const int c4 = t & 31;
    const int rg = t >> 5;
    const uint2* X4 = (const uint2*)X;
    float s0=0,s1=0,s2=0,s3=0,q0=0,q1=0,q2=0,q3=0;
    for (int r = blockIdx.x * 8 + rg; r < N; r += gridDim.x * 8) {
        uint2 v = X4[(size_t)r * 32 + c4];
        float f0 = u2f(v.x << 16), f1 = u2f(v.x & 0xffff0000u);
        float f2 = u2f(v.y << 16), f3 = u2f(v.y & 0xffff0000u);
        s0 += f0; q0 += f0 * f0;
        s1 += f1; q1 += f1 * f1;
        s2 += f2; q2 += f2 * f2;
        s3 += f3; q3 += f3 * f3;
    }
    __shared__ float ls[8][32][8];
    ls[rg][c4][0] = s0; ls[rg][c4][1] = s1; ls[rg][c4][2] = s2; ls[rg][c4][3] = s3;
    ls[rg][c4][4] = q0; ls[rg][c4][5] = q1; ls[rg][c4][6] = q2; ls[rg][c4][7] = q3;
    __syncthreads();
    if (t < 32) {
        float a[8] = {0,0,0,0,0,0,0,0};
        for (int g = 0; g < 8; ++g)
            for (int k = 0; k < 8; ++k) a[k] += ls[g][t][k];
        for (int k = 0; k < 4; ++k) {
            atomicAdd(&stats[t * 4 + k], a[k]);
            atomicAdd(&stats[128 + t * 4 + k], a[4 + k]);
        }
    }
}

__global__ void bn_finalize_kernel(float* __restrict__ stats, const float* __restrict__ g,
                                   const float* __restrict__ be, float invN) {
    int c = threadIdx.x;
    if (c < 128) {
        float mu  = stats[c] * invN;
        float var = stats[c + 128] * invN - mu * mu;
        float sc  = g[c] * rsqrtf(var + BN_EPS);
        stats[c]       = sc;
        stats[c + 128] = be[c] - mu * sc;
    }
}

// ---------------- host launch ----------------
extern "C" void kernel_launch(void* const* d_in, const int* in_sizes, int n_in,
                              void* d_out, int out_size, void* d_ws, size_t ws_size,
                              hipStream_t stream) {
    const float* x   = (const float*)d_in[0];
    const void*  eix = d_in[1];
    const float* W1  = (const float*)d_in[2];
    const float* b1  = (const float*)d_in[3];
    const float* g1  = (const float*)d_in[4];
    const float* be1 = (const float*)d_in[5];
    const float* W2  = (const float*)d_in[6];
    const float* b2  = (const float*)d_in[7];
    const float* g2  = (const float*)d_in[8];
    const float* be2 = (const float*)d_in[9];
    const float* W3  = (const float*)d_in[10];
    const float* b3  = (const float*)d_in[11];
    float* outp = (float*)d_out;

    const int N = in_sizes[0] / 128;
    const int E = in_sizes[1] / 2;
    const int NB = (N + (1 << BINSH) - 1) >> BINSH;

    char* base = (char*)d_ws;
    size_t off = 0;
    auto alloc = [&](size_t bytes) -> char* {
        char* p = base + off;
        off = (off + bytes + 255) & ~(size_t)255;
        return p;
    };
    __hip_bfloat16* A = (__hip_bfloat16*)alloc((size_t)N * 128 * 2); // hw (bf16)
    __hip_bfloat16* B = (__hip_bfloat16*)alloc((size_t)N * 128 * 2); // pre-BN h (bf16)
    int*   rp     = (int*)alloc((size_t)(N + 1) * 4);
    float* dis    = (float*)alloc((size_t)N * 4);
    int2*  ep     = (int2*)alloc((size_t)E * 8);
    int2*  ibuf   = (int2*)alloc((size_t)E * 8);
    int*   hist2d = (int*)alloc((size_t)NBLK * MAXNB * 4);
    int*   binhist= (int*)alloc(MAXNB * 4);
    int*   binrp  = (int*)alloc((MAXNB + 1) * 4);
    __hip_bfloat16* wt1 = (__hip_bfloat16*)alloc(128 * 128 * 2);
    __hip_bfloat16* wt2 = (__hip_bfloat16*)alloc(128 * 128 * 2);
    __hip_bfloat16* wt3 = (__hip_bfloat16*)alloc(64 * 128 * 2);
    float* stats1 = (float*)alloc(256 * 4);
    float* stats2 = (float*)alloc(256 * 4);
    int*   flag   = (int*)alloc(64);
    (void)ws_size; (void)n_in; (void)out_size;

    const int per_block = (E + NBLK - 1) / NBLK;

    // ---- graph preprocessing ----
    detect_kernel<<<1, 64, 0, stream>>>((const int*)eix, flag);
    hipMemsetAsync(binhist, 0, MAXNB * 4, stream);
    histA_kernel<<<NBLK, 256, 0, stream>>>(eix, flag, hist2d, binhist, E, NB, per_block);
    basescan_kernel<<<1, 256, 0, stream>>>(binhist, binrp, hist2d, NB, NBLK);
    passB_kernel<<<NBLK, 256, 0, stream>>>(eix, flag, hist2d, ibuf, E, NB, per_block);
    binsort2_kernel<<<NB, 256, 0, stream>>>(ibuf, binrp, rp, dis, ep, N);
    weight_kernel<<<(E + 255) / 256, 256, 0, stream>>>(ep, dis, E);

    // ---- weight transposes (bf16) ----
    prep_wt_kernel<<<64, 256, 0, stream>>>(W1, wt1, 128, 128);
    prep_wt_kernel<<<64, 256, 0, stream>>>(W2, wt2, 128, 128);
    prep_wt_kernel<<<32, 256, 0, stream>>>(W3, wt3, 128, 64);

    const float invN = 1.0f / (float)N;
    const int gemm_grid = (N + 63) / 64;
    const int agg128_grid  = (int)(((long long)N * 32 + 255) / 256);
    const int agg64_grid   = (int)(((long long)N * 16 + 255) / 256);

    // ---- layer 1 ----
    mfma_gemm_kernel<128, false, float><<<gemm_grid, 256, 0, stream>>>(x, wt1, nullptr, A, N);
    agg_kernel<128, true><<<agg128_grid, 256, 0, stream>>>(A, rp, ep, dis, b1, B, N);
    hipMemsetAsync(stats1, 0, 256 * 4, stream);
    bn_stats_kernel<<<256, 256, 0, stream>>>(B, stats1, N);
    bn_finalize_kernel<<<1, 128, 0, stream>>>(stats1, g1, be1, invN);

    // ---- layer 2 ----
    mfma_gemm_kernel<128, true, __hip_bfloat16><<<gemm_grid, 256, 0, stream>>>(B, wt2, stats1, A, N);
    agg_kernel<128, true><<<agg128_grid, 256, 0, stream>>>(A, rp, ep, dis, b2, B, N);
    hipMemsetAsync(stats2, 0, 256 * 4, stream);
    bn_stats_kernel<<<256, 256, 0, stream>>>(B, stats2, N);
    bn_finalize_kernel<<<1, 128, 0, stream>>>(stats2, g2, be2, invN);

    // ---- layer 3 ----
    mfma_gemm_kernel<64, true, __hip_bfloat16><<<gemm_grid, 256, 0, stream>>>(B, wt3, stats2, A, N);
    agg_kernel<64, false><<<agg64_grid, 256, 0, stream>>>(A, rp, ep, dis, b3, outp, N);
}

// Round 6
// 375.942 us; speedup vs baseline: 2.3492x; 1.1659x over previous
//
#include <hip/hip_runtime.h>
#include <hip/hip_bf16.h>

#define BN_EPS 1e-5f
#define BINSH 9
#define MAXNB 200
#define NBLK 256

typedef __attribute__((ext_vector_type(8))) short bf16x8v;
typedef __attribute__((ext_vector_type(4))) float f32x4v;

__device__ __forceinline__ float u2f(unsigned x) { return __uint_as_float(x); }
__device__ __forceinline__ unsigned short f2bf(float f) {
    union { __hip_bfloat16 h; unsigned short u; } cv;
    cv.h = __float2bfloat16(f);
    return cv.u;
}

// ---------------- edge dtype detection ----------------
__global__ void detect_kernel(const int* __restrict__ e32, int* __restrict__ flag) {
    if (threadIdx.x == 0 && blockIdx.x == 0) {
        int nz = 0;
        for (int i = 0; i < 64; ++i) nz += (e32[2*i + 1] != 0);
        *flag = (nz == 0) ? 1 : 0;
    }
}

__device__ __forceinline__ int edge_at(const void* p, long long i, int is64) {
    return is64 ? (int)((const long long*)p)[i] : ((const int*)p)[i];
}

// ---------------- pass A: per-block bin histogram (transposed out) ----------------
__global__ __launch_bounds__(256) void histA_kernel(const void* __restrict__ eidx,
                                                    const int* __restrict__ flag,
                                                    int* __restrict__ hist2dT,
                                                    int* __restrict__ binhist,
                                                    int E, int NB, int per_block) {
    __shared__ int lh[MAXNB];
    const int t = threadIdx.x;
    for (int i = t; i < NB; i += 256) lh[i] = 0;
    __syncthreads();
    const int is64 = *flag;
    long long base = (long long)blockIdx.x * per_block;
    long long lim  = base + per_block;
    if (lim > E) lim = E;
    for (long long e = base + t; e < lim; e += 256) {
        int d = edge_at(eidx, (long long)E + e, is64);
        atomicAdd(&lh[d >> BINSH], 1);
    }
    __syncthreads();
    for (int i = t; i < NB; i += 256) {
        hist2dT[i * NBLK + blockIdx.x] = lh[i];
        atomicAdd(&binhist[i], lh[i]);
    }
}

// ---------------- bin-level scan: binrp ----------------
__global__ void binscan_kernel(const int* __restrict__ binhist, int* __restrict__ binrp, int NB) {
    __shared__ int s[256];
    const int t = threadIdx.x;
    int v = (t < NB) ? binhist[t] : 0;
    s[t] = v;
    __syncthreads();
    for (int off = 1; off < 256; off <<= 1) {
        int x = (t >= off) ? s[t - off] : 0;
        __syncthreads();
        s[t] += x;
        __syncthreads();
    }
    if (t < NB) binrp[t] = s[t] - v;
    if (t == 0) binrp[NB] = s[255];
}

// ---------------- per-bin column scan (parallel, coalesced) ----------------
__global__ __launch_bounds__(256) void colscan_kernel(int* __restrict__ hist2dT,
                                                      const int* __restrict__ binrp) {
    __shared__ int s[256];
    const int b = blockIdx.x;
    const int t = threadIdx.x;
    int v = hist2dT[b * NBLK + t];
    s[t] = v;
    __syncthreads();
    for (int off = 1; off < 256; off <<= 1) {
        int x = (t >= off) ? s[t - off] : 0;
        __syncthreads();
        s[t] += x;
        __syncthreads();
    }
    hist2dT[b * NBLK + t] = binrp[b] + s[t] - v;
}

// ---------------- pass B: edge-parallel scatter into reserved ranges ----------------
__global__ __launch_bounds__(256) void passB_kernel(const void* __restrict__ eidx,
                                                    const int* __restrict__ flag,
                                                    const int* __restrict__ hist2dT,
                                                    int2* __restrict__ ibuf,
                                                    int E, int NB, int per_block) {
    __shared__ int lbase[MAXNB];
    __shared__ int lcur[MAXNB];
    const int t = threadIdx.x;
    for (int i = t; i < NB; i += 256) {
        lbase[i] = hist2dT[i * NBLK + blockIdx.x];
        lcur[i]  = 0;
    }
    __syncthreads();
    const int is64 = *flag;
    long long base = (long long)blockIdx.x * per_block;
    long long lim  = base + per_block;
    if (lim > E) lim = E;
    for (long long e = base + t; e < lim; e += 256) {
        int sN = edge_at(eidx, e, is64);
        int d  = edge_at(eidx, (long long)E + e, is64);
        int b  = d >> BINSH;
        int pos = lbase[b] + atomicAdd(&lcur[b], 1);
        ibuf[pos] = make_int2(sN, d);
    }
}

// ---------------- per-bin exact sort; computes rp + dis ----------------
__global__ __launch_bounds__(256) void binsort2_kernel(const int2* __restrict__ ibuf,
                                                       const int* __restrict__ binrp,
                                                       int* __restrict__ rp,
                                                       float* __restrict__ dis,
                                                       int2* __restrict__ ep, int N) {
    const int b  = blockIdx.x;
    const int d0 = b << BINSH;
    const int dc = min(1 << BINSH, N - d0);
    __shared__ int lcnt[1 << BINSH];
    __shared__ int lofs[1 << BINSH];
    __shared__ int s2[256];
    const int t = threadIdx.x;
    lcnt[t] = 0; lcnt[t + 256] = 0;
    __syncthreads();
    const int ib0 = binrp[b], ib1 = binrp[b + 1];
    const int nE  = ib1 - ib0;
    for (int i = t; i < nE; i += 256) {
        int2 sd = ibuf[ib0 + i];
        atomicAdd(&lcnt[sd.y - d0], 1);
    }
    __syncthreads();
    const int c0 = lcnt[2 * t], c1 = lcnt[2 * t + 1];
    const int pair = c0 + c1;
    s2[t] = pair;
    __syncthreads();
    for (int off = 1; off < 256; off <<= 1) {
        int x = (t >= off) ? s2[t - off] : 0;
        __syncthreads();
        s2[t] += x;
        __syncthreads();
    }
    const int pexcl = s2[t] - pair;
    if (2 * t < dc) {
        rp[d0 + 2 * t + 1] = ib0 + pexcl + c0;
        dis[d0 + 2 * t]    = rsqrtf((float)c0 + 1.0f);
    }
    if (2 * t + 1 < dc) {
        rp[d0 + 2 * t + 2] = ib0 + pexcl + pair;
        dis[d0 + 2 * t + 1] = rsqrtf((float)c1 + 1.0f);
    }
    if (b == 0 && t == 0) rp[0] = 0;
    lofs[2 * t]     = pexcl;
    lofs[2 * t + 1] = pexcl + c0;
    __syncthreads();
    for (int i = t; i < nE; i += 256) {
        int2 sd = ibuf[ib0 + i];
        int dl  = sd.y - d0;
        int pos = ib0 + atomicAdd(&lofs[dl], 1);
        ep[pos] = sd;
    }
}

// ---------------- weights: (src,dst) -> (src,w) in place ----------------
__global__ void weight_kernel(int2* __restrict__ ep, const float* __restrict__ dis, int E) {
    int e = blockIdx.x * 256 + threadIdx.x;
    if (e >= E) return;
    int2 sd = ep[e];
    float w = dis[sd.x] * dis[sd.y];
    ep[e] = make_int2(sd.x, __float_as_int(w));
}

// ---------------- W -> W^T bf16 prep ----------------
__global__ void prep_wt_kernel(const float* __restrict__ W, __hip_bfloat16* __restrict__ Wt,
                               int K, int DOUT) {
    int i = blockIdx.x * 256 + threadIdx.x;
    if (i < K * DOUT) {
        int k = i / DOUT, c = i % DOUT;
        Wt[c * K + k] = __float2bfloat16(W[i]);
    }
}

// ---------------- fragment loaders (8 k-values -> f32[8]) ----------------
__device__ __forceinline__ void load8(const float* p, float* f) {
    float4 v0 = ((const float4*)p)[0];
    float4 v1 = ((const float4*)p)[1];
    f[0] = v0.x; f[1] = v0.y; f[2] = v0.z; f[3] = v0.w;
    f[4] = v1.x; f[5] = v1.y; f[6] = v1.z; f[7] = v1.w;
}
__device__ __forceinline__ void load8(const __hip_bfloat16* p, float* f) {
    uint4 v = *(const uint4*)p;
    f[0] = u2f(v.x << 16); f[1] = u2f(v.x & 0xffff0000u);
    f[2] = u2f(v.y << 16); f[3] = u2f(v.y & 0xffff0000u);
    f[4] = u2f(v.z << 16); f[5] = u2f(v.z & 0xffff0000u);
    f[6] = u2f(v.w << 16); f[7] = u2f(v.w & 0xffff0000u);
}

// ---------------- MFMA GEMM: out[N][DOUT] = bnrelu(H)[N][128] @ W, bf16 out ----------------
template <int DOUT, bool BN, typename TH>
__global__ __launch_bounds__(256) void mfma_gemm_kernel(const TH* __restrict__ H,
                                                        const __hip_bfloat16* __restrict__ Wt,
                                                        const float* __restrict__ bnst,
                                                        __hip_bfloat16* __restrict__ out, int N) {
    constexpr int NCT = DOUT / 16;
    constexpr int LDW = 136;
    __shared__ __hip_bfloat16 sWt[DOUT * LDW];
    const int t = threadIdx.x;
    for (int i = t; i < DOUT * 16; i += 256) {
        int row = i >> 4, seg = i & 15;
        *(uint4*)&sWt[row * LDW + seg * 8] = ((const uint4*)Wt)[i];
    }
    const int lane = t & 63, wid = t >> 6;
    const int kq = lane >> 4, mrow = lane & 15;
    const int grow = blockIdx.x * 64 + wid * 16 + mrow;
    const int lrow = min(grow, N - 1);
    bf16x8v afrag[4];
#pragma unroll
    for (int ks = 0; ks < 4; ++ks) {
        const int k0 = ks * 32 + kq * 8;
        float f[8];
        load8(H + (size_t)lrow * 128 + k0, f);
        if (BN) {
            float4 s0 = *(const float4*)(bnst + k0);
            float4 s1 = *(const float4*)(bnst + k0 + 4);
            float4 h0 = *(const float4*)(bnst + 128 + k0);
            float4 h1 = *(const float4*)(bnst + 128 + k0 + 4);
            f[0] = fmaxf(fmaf(f[0], s0.x, h0.x), 0.f);
            f[1] = fmaxf(fmaf(f[1], s0.y, h0.y), 0.f);
            f[2] = fmaxf(fmaf(f[2], s0.z, h0.z), 0.f);
            f[3] = fmaxf(fmaf(f[3], s0.w, h0.w), 0.f);
            f[4] = fmaxf(fmaf(f[4], s1.x, h1.x), 0.f);
            f[5] = fmaxf(fmaf(f[5], s1.y, h1.y), 0.f);
            f[6] = fmaxf(fmaf(f[6], s1.z, h1.z), 0.f);
            f[7] = fmaxf(fmaf(f[7], s1.w, h1.w), 0.f);
        }
        bf16x8v a;
#pragma unroll
        for (int j = 0; j < 8; ++j) a[j] = (short)f2bf(f[j]);
        afrag[ks] = a;
    }
    __syncthreads();
    f32x4v acc[NCT];
#pragma unroll
    for (int ct = 0; ct < NCT; ++ct) acc[ct] = (f32x4v){0.f, 0.f, 0.f, 0.f};
#pragma unroll
    for (int ct = 0; ct < NCT; ++ct) {
#pragma unroll
        for (int ks = 0; ks < 4; ++ks) {
            bf16x8v b = *(const bf16x8v*)&sWt[(ct * 16 + mrow) * LDW + ks * 32 + kq * 8];
            acc[ct] = __builtin_amdgcn_mfma_f32_16x16x32_bf16(afrag[ks], b, acc[ct], 0, 0, 0);
        }
    }
#pragma unroll
    for (int r = 0; r < 4; ++r) {
        int orow = blockIdx.x * 64 + wid * 16 + kq * 4 + r;
        if (orow < N) {
            __hip_bfloat16* op = out + (size_t)orow * DOUT + mrow;
#pragma unroll
            for (int ct = 0; ct < NCT; ++ct) {
                union { unsigned short u; __hip_bfloat16 h; } cv;
                cv.u = f2bf(acc[ct][r]);
                op[ct * 16] = cv.h;
            }
        }
    }
}

// ---------------- aggregation: 4 cols/thread, 8x edge unroll ----------------
template <int D, bool OUTBF>
__global__ void agg_kernel(const __hip_bfloat16* __restrict__ hw, const int* __restrict__ rp,
                           const int2* __restrict__ ep, const float* __restrict__ dis,
                           const float* __restrict__ bias, void* __restrict__ outv, int N) {
    constexpr int LPR = D / 4;
    int gtid = blockIdx.x * blockDim.x + threadIdx.x;
    int n    = gtid / LPR;
    int lane = gtid % LPR;
    if (n >= N) return;
    const uint2* hw4 = (const uint2*)hw;
    float sn = dis[n];
    sn *= sn;
    uint2 hv = hw4[(size_t)n * LPR + lane];
    float a0 = u2f(hv.x << 16) * sn;
    float a1 = u2f(hv.x & 0xffff0000u) * sn;
    float a2 = u2f(hv.y << 16) * sn;
    float a3 = u2f(hv.y & 0xffff0000u) * sn;
    int e0 = rp[n], e1 = rp[n + 1];
    int e = e0;
    for (; e + 8 <= e1; e += 8) {
        int2 p[8];
        uint2 v[8];
#pragma unroll
        for (int j = 0; j < 8; ++j) p[j] = ep[e + j];
#pragma unroll
        for (int j = 0; j < 8; ++j) v[j] = hw4[(size_t)p[j].x * LPR + lane];
#pragma unroll
        for (int j = 0; j < 8; ++j) {
            float w = __int_as_float(p[j].y);
            a0 += u2f(v[j].x << 16) * w; a1 += u2f(v[j].x & 0xffff0000u) * w;
            a2 += u2f(v[j].y << 16) * w; a3 += u2f(v[j].y & 0xffff0000u) * w;
        }
    }
    for (; e + 4 <= e1; e += 4) {
        int2 p[4];
        uint2 v[4];
#pragma unroll
        for (int j = 0; j < 4; ++j) p[j] = ep[e + j];
#pragma unroll
        for (int j = 0; j < 4; ++j) v[j] = hw4[(size_t)p[j].x * LPR + lane];
#pragma unroll
        for (int j = 0; j < 4; ++j) {
            float w = __int_as_float(p[j].y);
            a0 += u2f(v[j].x << 16) * w; a1 += u2f(v[j].x & 0xffff0000u) * w;
            a2 += u2f(v[j].y << 16) * w; a3 += u2f(v[j].y & 0xffff0000u) * w;
        }
    }
    for (; e < e1; ++e) {
        int2 p = ep[e];
        uint2 v = hw4[(size_t)p.x * LPR + lane];
        float w = __int_as_float(p.y);
        a0 += u2f(v.x << 16) * w; a1 += u2f(v.x & 0xffff0000u) * w;
        a2 += u2f(v.y << 16) * w; a3 += u2f(v.y & 0xffff0000u) * w;
    }
    float4 bv = ((const float4*)bias)[lane];
    a0 += bv.x; a1 += bv.y; a2 += bv.z; a3 += bv.w;
    if (OUTBF) {
        ushort4 o;
        o.x = f2bf(a0); o.y = f2bf(a1); o.z = f2bf(a2); o.w = f2bf(a3);
        ((ushort4*)outv)[(size_t)n * LPR + lane] = o;
    } else {
        ((float4*)outv)[(size_t)n * LPR + lane] = make_float4(a0, a1, a2, a3);
    }
}

// ---------------- batchnorm stats (bf16 input) ----------------
__global__ void bn_stats_kernel(const __hip_bfloat16* __restrict__ X, float* __restrict__ stats, int N) {
    const int t  = threadIdx.x;
    const int c4 = t & 31;
    const int rg = t >> 5;
    const uint2* X4 = (const uint2*)X;
    float s0=0,s1=0,s2=0,s3=0,q0=0,q1=0,q2=0,q3=0;
    for (int r = blockIdx.x * 8 + rg; r < N; r += gridDim.x * 8) {
        uint2 v = X4[(size_t)r * 32 + c4];
        float f0 = u2f(v.x << 16), f1 = u2f(v.x & 0xffff0000u);
        float f2 = u2f(v.y << 16), f3 = u2f(v.y & 0xffff0000u);
        s0 += f0; q0 += f0 * f0;
        s1 += f1; q1 += f1 * f1;
        s2 += f2; q2 += f2 * f2;
        s3 += f3; q3 += f3 * f3;
    }
    __shared__ float ls[8][32][8];
    ls[rg][c4][0] = s0; ls[rg][c4][1] = s1; ls[rg][c4][2] = s2; ls[rg][c4][3] = s3;
    ls[rg][c4][4] = q0; ls[rg][c4][5] = q1; ls[rg][c4][6] = q2; ls[rg][c4][7] = q3;
    __syncthreads();
    if (t < 32) {
        float a[8] = {0,0,0,0,0,0,0,0};
        for (int g = 0; g < 8; ++g)
            for (int k = 0; k < 8; ++k) a[k] += ls[g][t][k];
        for (int k = 0; k < 4; ++k) {
            atomicAdd(&stats[t * 4 + k], a[k]);
            atomicAdd(&stats[128 + t * 4 + k], a[4 + k]);
        }
    }
}

__global__ void bn_finalize_kernel(float* __restrict__ stats, const float* __restrict__ g,
                                   const float* __restrict__ be, float invN) {
    int c = threadIdx.x;
    if (c < 128) {
        float mu  = stats[c] * invN;
        float var = stats[c + 128] * invN - mu * mu;
        float sc  = g[c] * rsqrtf(var + BN_EPS);
        stats[c]       = sc;
        stats[c + 128] = be[c] - mu * sc;
    }
}

// ---------------- host launch ----------------
extern "C" void kernel_launch(void* const* d_in, const int* in_sizes, int n_in,
                              void* d_out, int out_size, void* d_ws, size_t ws_size,
                              hipStream_t stream) {
    const float* x   = (const float*)d_in[0];
    const void*  eix = d_in[1];
    const float* W1  = (const float*)d_in[2];
    const float* b1  = (const float*)d_in[3];
    const float* g1  = (const float*)d_in[4];
    const float* be1 = (const float*)d_in[5];
    const float* W2  = (const float*)d_in[6];
    const float* b2  = (const float*)d_in[7];
    const float* g2  = (const float*)d_in[8];
    const float* be2 = (const float*)d_in[9];
    const float* W3  = (const float*)d_in[10];
    const float* b3  = (const float*)d_in[11];
    float* outp = (float*)d_out;

    const int N = in_sizes[0] / 128;
    const int E = in_sizes[1] / 2;
    const int NB = (N + (1 << BINSH) - 1) >> BINSH;

    char* base = (char*)d_ws;
    size_t off = 0;
    auto alloc = [&](size_t bytes) -> char* {
        char* p = base + off;
        off = (off + bytes + 255) & ~(size_t)255;
        return p;
    };
    __hip_bfloat16* A = (__hip_bfloat16*)alloc((size_t)N * 128 * 2);
    __hip_bfloat16* B = (__hip_bfloat16*)alloc((size_t)N * 128 * 2);
    int*   rp      = (int*)alloc((size_t)(N + 1) * 4);
    float* dis     = (float*)alloc((size_t)N * 4);
    int2*  ep      = (int2*)alloc((size_t)E * 8);
    int2*  ibuf    = (int2*)alloc((size_t)E * 8);
    int*   hist2dT = (int*)alloc((size_t)MAXNB * NBLK * 4);
    int*   binhist = (int*)alloc(MAXNB * 4);
    int*   binrp   = (int*)alloc((MAXNB + 1) * 4);
    __hip_bfloat16* wt1 = (__hip_bfloat16*)alloc(128 * 128 * 2);
    __hip_bfloat16* wt2 = (__hip_bfloat16*)alloc(128 * 128 * 2);
    __hip_bfloat16* wt3 = (__hip_bfloat16*)alloc(64 * 128 * 2);
    float* stats1 = (float*)alloc(256 * 4);
    float* stats2 = (float*)alloc(256 * 4);
    int*   flag   = (int*)alloc(64);
    (void)ws_size; (void)n_in; (void)out_size;

    const int per_block = (E + NBLK - 1) / NBLK;

    // ---- graph preprocessing ----
    detect_kernel<<<1, 64, 0, stream>>>((const int*)eix, flag);
    hipMemsetAsync(binhist, 0, MAXNB * 4, stream);
    histA_kernel<<<NBLK, 256, 0, stream>>>(eix, flag, hist2dT, binhist, E, NB, per_block);
    binscan_kernel<<<1, 256, 0, stream>>>(binhist, binrp, NB);
    colscan_kernel<<<NB, 256, 0, stream>>>(hist2dT, binrp);
    passB_kernel<<<NBLK, 256, 0, stream>>>(eix, flag, hist2dT, ibuf, E, NB, per_block);
    binsort2_kernel<<<NB, 256, 0, stream>>>(ibuf, binrp, rp, dis, ep, N);
    weight_kernel<<<(E + 255) / 256, 256, 0, stream>>>(ep, dis, E);

    // ---- weight transposes (bf16) ----
    prep_wt_kernel<<<64, 256, 0, stream>>>(W1, wt1, 128, 128);
    prep_wt_kernel<<<64, 256, 0, stream>>>(W2, wt2, 128, 128);
    prep_wt_kernel<<<32, 256, 0, stream>>>(W3, wt3, 128, 64);

    const float invN = 1.0f / (float)N;
    const int gemm_grid = (N + 63) / 64;
    const int agg128_grid  = (int)(((long long)N * 32 + 255) / 256);
    const int agg64_grid   = (int)(((long long)N * 16 + 255) / 256);

    // ---- layer 1 ----
    mfma_gemm_kernel<128, false, float><<<gemm_grid, 256, 0, stream>>>(x, wt1, nullptr, A, N);
    agg_kernel<128, true><<<agg128_grid, 256, 0, stream>>>(A, rp, ep, dis, b1, B, N);
    hipMemsetAsync(stats1, 0, 256 * 4, stream);
    bn_stats_kernel<<<256, 256, 0, stream>>>(B, stats1, N);
    bn_finalize_kernel<<<1, 128, 0, stream>>>(stats1, g1, be1, invN);

    // ---- layer 2 ----
    mfma_gemm_kernel<128, true, __hip_bfloat16><<<gemm_grid, 256, 0, stream>>>(B, wt2, stats1, A, N);
    agg_kernel<128, true><<<agg128_grid, 256, 0, stream>>>(A, rp, ep, dis, b2, B, N);
    hipMemsetAsync(stats2, 0, 256 * 4, stream);
    bn_stats_kernel<<<256, 256, 0, stream>>>(B, stats2, N);
    bn_finalize_kernel<<<1, 128, 0, stream>>>(stats2, g2, be2, invN);

    // ---- layer 3 ----
    mfma_gemm_kernel<64, true, __hip_bfloat16><<<gemm_grid, 256, 0, stream>>>(B, wt3, stats2, A, N);
    agg_kernel<64, false><<<agg64_grid, 256, 0, stream>>>(A, rp, ep, dis, b3, outp, N);
}